// Round 13
// baseline (457.435 us; speedup 1.0000x reference)
//
#include <hip/hip_runtime.h>
#include <hip/hip_bf16.h>

#define N_NODES  20000
#define MPAD     20096
#define N_EDGES  320000
#define N_EP     (N_EDGES + N_NODES)
#define D_IN     256
#define N_GRAPHS 32
#define HH1 4
#define CC1 128
#define HH2 4
#define CC2 64
#define MAXDEG   128

// ---- workspace layout (bytes) ----
#define XB_OFF      0ull                    // 10,289,152 : x bf16 [MPAD,256]
#define HB1_OFF     10289152ull             // 20,578,304 : h1 bf16 [MPAD,512]
#define AGG1_OFF    30867456ull             // 20,578,304 : agg1 bf16 [MPAD,512] (raw, pre-BN)
#define HB2_OFF     51445760ull             // 10,289,152 : h2 bf16 [MPAD,256]
#define OUT2_OFF    61734912ull             //  5,120,000 : head-mean fp32 [20000,64] (pre-BN)
#define EAF_OFF     66854912ull             //  1,280,000
#define W1BT_OFF    68134912ull             //    262,144
#define W2BT_OFF    68397056ull             //    262,144
#define CSR_OFF     68659200ull             //  2,720,000 (int2: s, edge-id -> s, eav-bits)
#define ROWPTR_OFF  71379200ull             //     80,064
#define GSTART_OFF  71459264ull             //        256
#define SMALL_OFF   71459520ull             //     25,600
#define SBUF_OFF    71485120ull             //         64
#define EAP_OFF     71485184ull             //      1,280
#define ALSP_OFF    71486464ull             //    643,072 : al partials [MPAD*4][2]
#define ALDP_OFF    72129536ull             //    643,072
#define PMU1_OFF    72772608ull             //    524,288
#define PM21_OFF    73296896ull             //    524,288
#define PMU2_OFF    73821184ull             //     65,536
#define PM22_OFF    73886720ull             //     65,536
#define A1_OFF      73952256ull             //      2,048
#define B1_OFF      73954304ull             //      2,048
#define A2_OFF      73956352ull             //        256
#define B2_OFF      73956608ull             //        256
#define EAACC_OFF   73956864ull             //         64
#define ALS_OFF     73956928ull             //    321,536 : combined als [MPAD*4]
#define ALD_OFF     74278464ull             //    321,536
// ---- zeroed-at-start region ----
#define DEG_OFF     74600000ull             //     80,000
#define CURS_OFF    74680000ull             //     80,000
#define FLAGZ_OFF   74760000ull             //        128
#define ZERO0_START DEG_OFF
#define ZERO0_SIZE  160128ull
#define PP_OFF      74760128ull             //     65,536 : pool partials [256][64]

// small-region float offsets
#define S_AS1 0
#define S_AD1 512
#define S_WE1 1024
#define S_AE1 1536
#define S_G1  2048
#define S_BE1 2560
#define S_AS2 3072
#define S_AD2 3328
#define S_WE2 3584
#define S_AE2 3840
#define S_G2  4096
#define S_BE2 4160
#define S_FW1 4224
#define S_FB1 6272
#define S_FW2 6304
#define S_FB2 6336

typedef __attribute__((ext_vector_type(8))) short bf8_t;
typedef __attribute__((ext_vector_type(4))) float f4_t;

// ---- detect fp32 (1) vs bf16 (0); flag pre-zeroed ----
__global__ void detect_dtype(const unsigned short* __restrict__ xr, int* __restrict__ flag) {
    int i = blockIdx.x * blockDim.x + threadIdx.x;
    unsigned short u = xr[i];
    if ((u & 0x7F80) == 0x7F80) atomicOr(flag, 1);
}

__device__ __forceinline__ float loadF(const void* p, int i, int fp32) {
    return fp32 ? ((const float*)p)[i]
                : __bfloat162float(((const __hip_bfloat16*)p)[i]);
}

// ---- fused prep ----
#define PB_XB  5024
#define PB_EAF 313
#define PB_W   512
#define PB_SM  16
#define PREP_BLOCKS (PB_XB + PB_EAF + 2 * PB_W + PB_SM + 1)
__global__ __launch_bounds__(256) void prep(
        const int* __restrict__ flag,
        const void* x, const void* ea, const void* W1, const void* W2,
        const void* as1, const void* ad1, const void* We1, const void* ae1,
        const void* g1, const void* be1, const void* as2, const void* ad2,
        const void* We2, const void* ae2, const void* g2, const void* be2,
        const void* fw1, const void* fb1, const void* fw2, const void* fb2,
        __hip_bfloat16* __restrict__ xb, float* __restrict__ eaf, float* __restrict__ eap,
        __hip_bfloat16* __restrict__ W1bt, __hip_bfloat16* __restrict__ W2bt,
        float* __restrict__ smalls, float* __restrict__ sbuf) {
    __shared__ float sh[256];
    int b = blockIdx.x, t = threadIdx.x;
    int fp32 = flag[0];
    if (b < PB_XB) {
        int base = (b * 256 + t) * 4;
        __hip_bfloat16 tmp[4];
#pragma unroll
        for (int j = 0; j < 4; ++j) {
            int i = base + j;
            float v = (i < N_NODES * D_IN) ? loadF(x, i, fp32) : 0.f;
            tmp[j] = __float2bfloat16(v);
        }
        *(uint2*)&xb[base] = *(uint2*)tmp;
        return;
    }
    b -= PB_XB;
    if (b < PB_EAF) {
        int base = (b * 256 + t) * 4;
        float s = 0.f;
#pragma unroll
        for (int j = 0; j < 4; ++j) {
            int i = base + j;
            if (i < N_EDGES) { float v = loadF(ea, i, fp32); eaf[i] = v; s += v; }
        }
        sh[t] = s;
        __syncthreads();
        for (int st = 128; st; st >>= 1) {
            if (t < st) sh[t] += sh[t + st];
            __syncthreads();
        }
        if (t == 0) eap[b] = sh[0];
        return;
    }
    b -= PB_EAF;
    if (b < PB_W) {
        int i = b * 256 + t;
        int k = i >> 9, n = i & 511;
        W1bt[(size_t)n * 256 + k] = __float2bfloat16(loadF(W1, i, fp32));
        return;
    }
    b -= PB_W;
    if (b < PB_W) {
        int i = b * 256 + t;
        int k = i >> 8, n = i & 255;
        W2bt[(size_t)n * 512 + k] = __float2bfloat16(loadF(W2, i, fp32));
        return;
    }
    b -= PB_W;
    if (b < PB_SM) {
        const void* srcs[16] = {as1, ad1, We1, ae1, g1, be1, as2, ad2, We2, ae2, g2, be2, fw1, fb1, fw2, fb2};
        const int cnts[16] = {512, 512, 512, 512, 512, 512, 256, 256, 256, 256, 64, 64, 2048, 32, 32, 1};
        const int offs[16] = {S_AS1, S_AD1, S_WE1, S_AE1, S_G1, S_BE1, S_AS2, S_AD2,
                              S_WE2, S_AE2, S_G2, S_BE2, S_FW1, S_FB1, S_FW2, S_FB2};
        for (int i = t; i < cnts[b]; i += 256)
            smalls[offs[b] + i] = loadF(srcs[b], i, fp32);
        return;
    }
    if (t < 4) {
        float s = 0.f;
        for (int c = 0; c < CC1; ++c) s += loadF(We1, t * CC1 + c, fp32) * loadF(ae1, t * CC1 + c, fp32);
        sbuf[t] = s;
    } else if (t < 8) {
        int h = t - 4;
        float s = 0.f;
        for (int c = 0; c < CC2; ++c) s += loadF(We2, h * CC2 + c, fp32) * loadF(ae2, h * CC2 + c, fp32);
        sbuf[4 + h] = s;
    }
}

// ---- fused hist + graph bounds ----
#define HIST_BLOCKS 1329
__global__ void hist_bounds(const int* __restrict__ ei, int* __restrict__ deg,
                            const int* __restrict__ batch, int* __restrict__ gstart) {
    int b = blockIdx.x, t = threadIdx.x;
    if (b < HIST_BLOCKS) {
        int e = b * 256 + t;
        if (e >= N_EP) return;
        int d = (e < N_EDGES) ? ei[N_EDGES + e] : e - N_EDGES;
        atomicAdd(&deg[d], 1);
        return;
    }
    int i = (b - HIST_BLOCKS) * 256 + t;
    if (i >= N_NODES) return;
    int bb = batch[i];
    if (i == 0) {
        for (int g = 0; g <= bb; ++g) gstart[g] = 0;
    } else {
        int pb = batch[i - 1];
        for (int g = pb + 1; g <= bb; ++g) gstart[g] = i;
    }
    if (i == N_NODES - 1) {
        for (int g = bb + 1; g <= N_GRAPHS; ++g) gstart[g] = N_NODES;
    }
}

__global__ __launch_bounds__(1024) void deg_scan(const int* __restrict__ deg, int* __restrict__ rowptr,
                                                 const float* __restrict__ eap, float* __restrict__ ea_acc) {
    __shared__ int part[1024];
    int t = threadIdx.x;
    int lo = t * 20;
    int hi = lo + 20; if (hi > N_NODES) hi = N_NODES; if (lo > N_NODES) lo = N_NODES;
    int s = 0;
    for (int i = lo; i < hi; ++i) s += deg[i];
    part[t] = s;
    __syncthreads();
    for (int off = 1; off < 1024; off <<= 1) {
        int u = (t >= off) ? part[t - off] : 0;
        __syncthreads();
        if (t >= off) part[t] += u;
        __syncthreads();
    }
    int run = part[t] - s;
    for (int i = lo; i < hi; ++i) { rowptr[i] = run; run += deg[i]; }
    if (hi == N_NODES && lo < N_NODES) rowptr[N_NODES] = run;
    if (t == 0) {
        float es = 0.f;
        for (int i = 0; i < PB_EAF; ++i) es += eap[i];
        ea_acc[0] = es;
    }
}

__global__ void edge_scatter(const int* __restrict__ ei, const int* __restrict__ rowptr,
                             int* __restrict__ cursor, int2* __restrict__ csr_se) {
    int e = blockIdx.x * blockDim.x + threadIdx.x;
    if (e >= N_EP) return;
    int s, d;
    if (e < N_EDGES) { s = ei[e]; d = ei[N_EDGES + e]; }
    else { s = d = e - N_EDGES; }
    int pos = rowptr[d] + atomicAdd(&cursor[d], 1);
    csr_se[pos] = make_int2(s, e);
}

// ---- canonical CSR order: sort each segment by edge id ----
__global__ __launch_bounds__(64) void csr_sort(const int* __restrict__ rowptr, int2* __restrict__ cs) {
    __shared__ int2 buf[128];
    int d = blockIdx.x;
    int beg = rowptr[d], end = rowptr[d + 1], n = end - beg;
    int lane = threadIdx.x;
    if (n <= 1) return;
    if (n <= 128) {
        for (int i = lane; i < n; i += 64) buf[i] = cs[beg + i];
        __syncthreads();
        if (lane == 0) {
            for (int i = 1; i < n; ++i) {
                int2 key = buf[i]; int j = i - 1;
                while (j >= 0 && buf[j].y > key.y) { buf[j + 1] = buf[j]; --j; }
                buf[j + 1] = key;
            }
        }
        __syncthreads();
        for (int i = lane; i < n; i += 64) cs[beg + i] = buf[i];
    } else if (lane == 0) {
        for (int i = beg + 1; i < end; ++i) {
            int2 key = cs[i]; int j = i - 1;
            while (j >= beg && cs[j].y > key.y) { cs[j + 1] = cs[j]; --j; }
            cs[j + 1] = key;
        }
    }
}

// ---- replace edge id with eav (float bits) in CSR (deterministic, in-place) ----
__global__ void csr_fill(int2* __restrict__ cs, const float* __restrict__ eaf,
                         const float* __restrict__ ea_acc) {
    int p = blockIdx.x * blockDim.x + threadIdx.x;
    if (p >= N_EP) return;
    int e = cs[p].y;
    float eav = (e < N_EDGES) ? eaf[e] : ea_acc[0] * (1.0f / N_EDGES);
    cs[p].y = __float_as_int(eav);
}

// ---- MFMA bf16 GEMM + al epilogue; optional BN+ELU applied to A during staging ----
template <bool BNA>
__global__ __launch_bounds__(256) void gemm_mfma_al(
        const short* __restrict__ A, const short* __restrict__ Bt,
        __hip_bfloat16* __restrict__ Cb, int N, int K,
        float* __restrict__ alsp, float* __restrict__ aldp,
        const float* __restrict__ asv, const float* __restrict__ adv, int cshift,
        const float* __restrict__ a1, const float* __restrict__ b1) {
    __shared__ short As[128 * 40];
    __shared__ short Bs[64 * 40];
    int t = threadIdx.x;
    int wv = t >> 6, lane = t & 63, quad = lane >> 4, lr = lane & 15;
    int m0 = blockIdx.y * 128, n0 = blockIdx.x * 64;
    f4_t acc[2][4] = {};
    int ra0 = t >> 2, sa0 = t & 3;
    int ra1 = (t + 256) >> 2;
    for (int k0 = 0; k0 < K; k0 += 32) {
        int j0 = k0 + sa0 * 8;
        {
            uint4 raw = *(const uint4*)&A[(size_t)(m0 + ra0) * K + j0];
            if (BNA) {
                unsigned short us[8]; *(uint4*)us = raw;
                __hip_bfloat16 ob[8];
#pragma unroll
                for (int i2 = 0; i2 < 8; ++i2) {
                    float v = __uint_as_float(((unsigned)us[i2]) << 16);
                    float y = a1[j0 + i2] * v + b1[j0 + i2];
                    y = y > 0.f ? y : expm1f(y);
                    ob[i2] = __float2bfloat16(y);
                }
                raw = *(uint4*)ob;
            }
            *(uint4*)&As[ra0 * 40 + sa0 * 8] = raw;
        }
        {
            uint4 raw = *(const uint4*)&A[(size_t)(m0 + ra1) * K + j0];
            if (BNA) {
                unsigned short us[8]; *(uint4*)us = raw;
                __hip_bfloat16 ob[8];
#pragma unroll
                for (int i2 = 0; i2 < 8; ++i2) {
                    float v = __uint_as_float(((unsigned)us[i2]) << 16);
                    float y = a1[j0 + i2] * v + b1[j0 + i2];
                    y = y > 0.f ? y : expm1f(y);
                    ob[i2] = __float2bfloat16(y);
                }
                raw = *(uint4*)ob;
            }
            *(uint4*)&As[ra1 * 40 + sa0 * 8] = raw;
        }
        *(uint4*)&Bs[ra0 * 40 + sa0 * 8] = *(const uint4*)&Bt[(size_t)(n0 + ra0) * K + k0 + sa0 * 8];
        __syncthreads();
        bf8_t a0 = *(const bf8_t*)&As[(wv * 16 + lr) * 40 + quad * 8];
        bf8_t a1f = *(const bf8_t*)&As[((wv + 4) * 16 + lr) * 40 + quad * 8];
#pragma unroll
        for (int nt = 0; nt < 4; ++nt) {
            bf8_t b = *(const bf8_t*)&Bs[(nt * 16 + lr) * 40 + quad * 8];
            acc[0][nt] = __builtin_amdgcn_mfma_f32_16x16x32_bf16(a0, b, acc[0][nt], 0, 0, 0);
            acc[1][nt] = __builtin_amdgcn_mfma_f32_16x16x32_bf16(a1f, b, acc[1][nt], 0, 0, 0);
        }
        __syncthreads();
    }
#pragma unroll
    for (int si = 0; si < 2; ++si) {
        int mrow = m0 + (wv + si * 4) * 16 + quad * 4;
#pragma unroll
        for (int nt = 0; nt < 4; ++nt) {
            int col = n0 + nt * 16 + lr;
#pragma unroll
            for (int r = 0; r < 4; ++r)
                Cb[(size_t)(mrow + r) * N + col] = __float2bfloat16(acc[si][nt][r]);
        }
    }
    float asv4[4], adv4[4];
#pragma unroll
    for (int nt = 0; nt < 4; ++nt) {
        asv4[nt] = asv[n0 + nt * 16 + lr];
        adv4[nt] = adv[n0 + nt * 16 + lr];
    }
    int hsel = n0 >> cshift;
    int parity = (n0 >> 6) & ((1 << (cshift - 6)) - 1);
#pragma unroll
    for (int si = 0; si < 2; ++si) {
#pragma unroll
        for (int r = 0; r < 4; ++r) {
            float ps = 0.f, pd = 0.f;
#pragma unroll
            for (int nt = 0; nt < 4; ++nt) {
                ps += acc[si][nt][r] * asv4[nt];
                pd += acc[si][nt][r] * adv4[nt];
            }
#pragma unroll
            for (int m = 1; m < 16; m <<= 1) {
                ps += __shfl_xor(ps, m);
                pd += __shfl_xor(pd, m);
            }
            if (lr == 0) {
                int row = m0 + (wv + si * 4) * 16 + quad * 4 + r;
                alsp[(row * 4 + hsel) * 2 + parity] = ps;
                aldp[(row * 4 + hsel) * 2 + parity] = pd;
            }
        }
    }
}

// ---- combine al partials in fixed order ----
__global__ void al_combine(const float* __restrict__ alsp, const float* __restrict__ aldp,
                           float* __restrict__ als, float* __restrict__ ald, int nparts) {
    int i = blockIdx.x * blockDim.x + threadIdx.x;
    if (i >= MPAD * 4) return;
    float s = alsp[2 * i], d0 = aldp[2 * i];
    if (nparts == 2) { s += alsp[2 * i + 1]; d0 += aldp[2 * i + 1]; }
    als[i] = s; ald[i] = d0;
}

// ---- FUSED deterministic softmax+agg, layer 1: 128 thr/dst, bf16 out [MPAD,512] ----
__global__ __launch_bounds__(128) void fused_agg1(
        const int* __restrict__ rowptr, const int2* __restrict__ cs,
        const float* __restrict__ als, const float* __restrict__ ald,
        const float* __restrict__ sbuf, const __hip_bfloat16* __restrict__ hb,
        __hip_bfloat16* __restrict__ outb) {
    __shared__ float lg[MAXDEG * 4];
    __shared__ int   ssrc[MAXDEG];
    __shared__ float red[4 * 128];
    __shared__ float mxs[4], dns[4];
    int d = blockIdx.x, t = threadIdx.x;
    int beg = rowptr[d], end = rowptr[d + 1], n = end - beg;
    bool fit = (n <= MAXDEG);
    float4 adv = *(const float4*)&ald[d * 4];
    float adh[4] = {adv.x, adv.y, adv.z, adv.w};
    float sb[4] = {sbuf[0], sbuf[1], sbuf[2], sbuf[3]};
    float mx[4] = {-INFINITY, -INFINITY, -INFINITY, -INFINITY};
    for (int p = t; p < n; p += 128) {
        int2 se = cs[beg + p];
        float eav = __int_as_float(se.y);
        float4 as = *(const float4*)&als[se.x * 4];
        float as4[4] = {as.x, as.y, as.z, as.w};
#pragma unroll
        for (int h = 0; h < 4; ++h) {
            float l = as4[h] + adh[h] + eav * sb[h];
            l = l > 0.f ? l : 0.2f * l;
            if (fit) lg[p * 4 + h] = l;
            mx[h] = fmaxf(mx[h], l);
        }
        if (fit) ssrc[p] = se.x;
    }
#pragma unroll
    for (int i = 0; i < 4; ++i) red[i * 128 + t] = mx[i];
    __syncthreads();
    for (int s = 64; s; s >>= 1) {
        if (t < s) {
#pragma unroll
            for (int i = 0; i < 4; ++i)
                red[i * 128 + t] = fmaxf(red[i * 128 + t], red[i * 128 + t + s]);
        }
        __syncthreads();
    }
    if (t < 4) mxs[t] = red[t * 128];
    __syncthreads();
    float m4[4] = {mxs[0], mxs[1], mxs[2], mxs[3]};
    float sm[4] = {0.f, 0.f, 0.f, 0.f};
    if (fit) {
        for (int p = t; p < n; p += 128) {
            float4 lv = *(float4*)&lg[p * 4];
            lv.x = __expf(lv.x - m4[0]); lv.y = __expf(lv.y - m4[1]);
            lv.z = __expf(lv.z - m4[2]); lv.w = __expf(lv.w - m4[3]);
            *(float4*)&lg[p * 4] = lv;
            sm[0] += lv.x; sm[1] += lv.y; sm[2] += lv.z; sm[3] += lv.w;
        }
    } else {
        for (int p = t; p < n; p += 128) {
            int2 se = cs[beg + p];
            float eav = __int_as_float(se.y);
            float4 as = *(const float4*)&als[se.x * 4];
            float as4[4] = {as.x, as.y, as.z, as.w};
#pragma unroll
            for (int h = 0; h < 4; ++h) {
                float l = as4[h] + adh[h] + eav * sb[h];
                l = l > 0.f ? l : 0.2f * l;
                sm[h] += __expf(l - m4[h]);
            }
        }
    }
    __syncthreads();
#pragma unroll
    for (int i = 0; i < 4; ++i) red[i * 128 + t] = sm[i];
    __syncthreads();
    for (int s = 64; s; s >>= 1) {
        if (t < s) {
#pragma unroll
            for (int i = 0; i < 4; ++i)
                red[i * 128 + t] += red[i * 128 + t + s];
        }
        __syncthreads();
    }
    if (t < 4) dns[t] = red[t * 128];
    __syncthreads();
    int h = t >> 5;
    float rdn = 1.0f / (dns[h] + 1e-16f);
    float a0 = 0.f, a1 = 0.f, a2 = 0.f, a3 = 0.f;
    if (fit) {
        for (int p = 0; p < n; ++p) {
            float w = lg[p * 4 + h];
            uint2 raw = *(const uint2*)&hb[(size_t)ssrc[p] * 512 + 4 * t];
            a0 += w * __uint_as_float(raw.x << 16);
            a1 += w * __uint_as_float(raw.x & 0xFFFF0000u);
            a2 += w * __uint_as_float(raw.y << 16);
            a3 += w * __uint_as_float(raw.y & 0xFFFF0000u);
        }
    } else {
        for (int p = 0; p < n; ++p) {
            int2 se = cs[beg + p];
            float eav = __int_as_float(se.y);
            float l = als[se.x * 4 + h] + adh[h] + eav * sb[h];
            l = l > 0.f ? l : 0.2f * l;
            float w = __expf(l - m4[h]);
            uint2 raw = *(const uint2*)&hb[(size_t)se.x * 512 + 4 * t];
            a0 += w * __uint_as_float(raw.x << 16);
            a1 += w * __uint_as_float(raw.x & 0xFFFF0000u);
            a2 += w * __uint_as_float(raw.y << 16);
            a3 += w * __uint_as_float(raw.y & 0xFFFF0000u);
        }
    }
    __hip_bfloat16 tmp[4] = {__float2bfloat16(a0 * rdn), __float2bfloat16(a1 * rdn),
                             __float2bfloat16(a2 * rdn), __float2bfloat16(a3 * rdn)};
    *(uint2*)&outb[(size_t)d * 512 + 4 * t] = *(uint2*)tmp;
}

// ---- FUSED softmax+agg+head-mean, layer 2: 64 thr/dst, fp32 out [20000,64] ----
__global__ __launch_bounds__(64) void fused_agg2(
        const int* __restrict__ rowptr, const int2* __restrict__ cs,
        const float* __restrict__ als, const float* __restrict__ ald,
        const float* __restrict__ sbuf, const __hip_bfloat16* __restrict__ hb,
        float* __restrict__ out2) {
    __shared__ float lg[MAXDEG * 4];
    __shared__ int   ssrc[MAXDEG];
    __shared__ float red[4 * 64];
    __shared__ float mxs[4], dns[4];
    __shared__ float shm[256];
    int d = blockIdx.x, t = threadIdx.x;
    int beg = rowptr[d], end = rowptr[d + 1], n = end - beg;
    bool fit = (n <= MAXDEG);
    float4 adv = *(const float4*)&ald[d * 4];
    float adh[4] = {adv.x, adv.y, adv.z, adv.w};
    float sb[4] = {sbuf[4], sbuf[5], sbuf[6], sbuf[7]};
    float mx[4] = {-INFINITY, -INFINITY, -INFINITY, -INFINITY};
    for (int p = t; p < n; p += 64) {
        int2 se = cs[beg + p];
        float eav = __int_as_float(se.y);
        float4 as = *(const float4*)&als[se.x * 4];
        float as4[4] = {as.x, as.y, as.z, as.w};
#pragma unroll
        for (int h = 0; h < 4; ++h) {
            float l = as4[h] + adh[h] + eav * sb[h];
            l = l > 0.f ? l : 0.2f * l;
            if (fit) lg[p * 4 + h] = l;
            mx[h] = fmaxf(mx[h], l);
        }
        if (fit) ssrc[p] = se.x;
    }
#pragma unroll
    for (int i = 0; i < 4; ++i) red[i * 64 + t] = mx[i];
    __syncthreads();
    for (int s = 32; s; s >>= 1) {
        if (t < s) {
#pragma unroll
            for (int i = 0; i < 4; ++i)
                red[i * 64 + t] = fmaxf(red[i * 64 + t], red[i * 64 + t + s]);
        }
        __syncthreads();
    }
    if (t < 4) mxs[t] = red[t * 64];
    __syncthreads();
    float m4[4] = {mxs[0], mxs[1], mxs[2], mxs[3]};
    float sm[4] = {0.f, 0.f, 0.f, 0.f};
    if (fit) {
        for (int p = t; p < n; p += 64) {
            float4 lv = *(float4*)&lg[p * 4];
            lv.x = __expf(lv.x - m4[0]); lv.y = __expf(lv.y - m4[1]);
            lv.z = __expf(lv.z - m4[2]); lv.w = __expf(lv.w - m4[3]);
            *(float4*)&lg[p * 4] = lv;
            sm[0] += lv.x; sm[1] += lv.y; sm[2] += lv.z; sm[3] += lv.w;
        }
    } else {
        for (int p = t; p < n; p += 64) {
            int2 se = cs[beg + p];
            float eav = __int_as_float(se.y);
            float4 as = *(const float4*)&als[se.x * 4];
            float as4[4] = {as.x, as.y, as.z, as.w};
#pragma unroll
            for (int h = 0; h < 4; ++h) {
                float l = as4[h] + adh[h] + eav * sb[h];
                l = l > 0.f ? l : 0.2f * l;
                sm[h] += __expf(l - m4[h]);
            }
        }
    }
    __syncthreads();
#pragma unroll
    for (int i = 0; i < 4; ++i) red[i * 64 + t] = sm[i];
    __syncthreads();
    for (int s = 32; s; s >>= 1) {
        if (t < s) {
#pragma unroll
            for (int i = 0; i < 4; ++i)
                red[i * 64 + t] += red[i * 64 + t + s];
        }
        __syncthreads();
    }
    if (t < 4) dns[t] = red[t * 64];
    __syncthreads();
    int h = t >> 4;
    float rdn = 1.0f / (dns[h] + 1e-16f);
    float a0 = 0.f, a1 = 0.f, a2 = 0.f, a3 = 0.f;
    if (fit) {
        for (int p = 0; p < n; ++p) {
            float w = lg[p * 4 + h];
            uint2 raw = *(const uint2*)&hb[(size_t)ssrc[p] * 256 + 4 * t];
            a0 += w * __uint_as_float(raw.x << 16);
            a1 += w * __uint_as_float(raw.x & 0xFFFF0000u);
            a2 += w * __uint_as_float(raw.y << 16);
            a3 += w * __uint_as_float(raw.y & 0xFFFF0000u);
        }
    } else {
        for (int p = 0; p < n; ++p) {
            int2 se = cs[beg + p];
            float eav = __int_as_float(se.y);
            float l = als[se.x * 4 + h] + adh[h] + eav * sb[h];
            l = l > 0.f ? l : 0.2f * l;
            float w = __expf(l - m4[h]);
            uint2 raw = *(const uint2*)&hb[(size_t)se.x * 256 + 4 * t];
            a0 += w * __uint_as_float(raw.x << 16);
            a1 += w * __uint_as_float(raw.x & 0xFFFF0000u);
            a2 += w * __uint_as_float(raw.y << 16);
            a3 += w * __uint_as_float(raw.y & 0xFFFF0000u);
        }
    }
    shm[4 * t] = a0 * rdn; shm[4 * t + 1] = a1 * rdn;
    shm[4 * t + 2] = a2 * rdn; shm[4 * t + 3] = a3 * rdn;
    __syncthreads();
    if (t < 16) {
        float4 v;
        v.x = 0.25f * (shm[4 * t] + shm[64 + 4 * t] + shm[128 + 4 * t] + shm[192 + 4 * t]);
        v.y = 0.25f * (shm[4 * t + 1] + shm[64 + 4 * t + 1] + shm[128 + 4 * t + 1] + shm[192 + 4 * t + 1]);
        v.z = 0.25f * (shm[4 * t + 2] + shm[64 + 4 * t + 2] + shm[128 + 4 * t + 2] + shm[192 + 4 * t + 2]);
        v.w = 0.25f * (shm[4 * t + 3] + shm[64 + 4 * t + 3] + shm[128 + 4 * t + 3] + shm[192 + 4 * t + 3]);
        *(float4*)&out2[(size_t)d * 64 + 4 * t] = v;
    }
}

// ---- BN1 stats: per-block partials (reads raw agg1) ----
__global__ __launch_bounds__(256) void bn_part_b(const __hip_bfloat16* __restrict__ x,
                                                 float* __restrict__ pmu, float* __restrict__ pm2) {
    int t = threadIdx.x, b = blockIdx.x;
    float s0 = 0.f, s20 = 0.f, s1 = 0.f, s21 = 0.f;
    for (int i = b; i < N_NODES; i += gridDim.x) {
        unsigned u = *(const unsigned*)&x[(size_t)i * 512 + 2 * t];
        float v0 = __uint_as_float(u << 16);
        float v1 = __uint_as_float(u & 0xFFFF0000u);
        s0 += v0; s20 += v0 * v0; s1 += v1; s21 += v1 * v1;
    }
    pmu[b * 512 + 2 * t] = s0;     pm2[b * 512 + 2 * t] = s20;
    pmu[b * 512 + 2 * t + 1] = s1; pm2[b * 512 + 2 * t + 1] = s21;
}

// ---- reduce partials -> affine a,b (fixed order) ----
__global__ void bn_reduce_affine(const float* __restrict__ pmu, const float* __restrict__ pm2,
                                 const float* __restrict__ smalls, int s_g, int s_be,
                                 float* __restrict__ a, float* __restrict__ b, int nch) {
    int c = blockIdx.x * blockDim.x + threadIdx.x;
    if (c >= nch) return;
    float s = 0.f, s2 = 0.f;
    for (int bk = 0; bk < 256; ++bk) { s += pmu[bk * nch + c]; s2 += pm2[bk * nch + c]; }
    float m = s * (1.0f / N_NODES);
    float var = s2 * (1.0f / N_NODES) - m * m;
    float aa = smalls[s_g + c] * rsqrtf(var + 1e-5f);
    a[c] = aa;
    b[c] = smalls[s_be + c] - m * aa;
}

// ---- BN2 stats: per-block partials ----
__global__ __launch_bounds__(256) void bn2_stats(const float* __restrict__ x,
                                                 float* __restrict__ pmu, float* __restrict__ pm2) {
    int t = threadIdx.x;
    int c = t & 63, j = t >> 6;
    float ls = 0.f, ls2 = 0.f;
    for (int nd = blockIdx.x * 4 + j; nd < N_NODES; nd += gridDim.x * 4) {
        float v = x[(size_t)nd * 64 + c];
        ls += v; ls2 += v * v;
    }
    __shared__ float shs[4][64], sh2[4][64];
    shs[j][c] = ls; sh2[j][c] = ls2;
    __syncthreads();
    if (j == 0) {
        pmu[blockIdx.x * 64 + c] = shs[0][c] + shs[1][c] + shs[2][c] + shs[3][c];
        pm2[blockIdx.x * 64 + c] = sh2[0][c] + sh2[1][c] + sh2[2][c] + sh2[3][c];
    }
}

// ---- pool stage 1: 8 chunks per graph, BN2 affine+ELU fused, partial sums ----
__global__ __launch_bounds__(256) void pool_part(const float* __restrict__ x, const int* __restrict__ gstart,
                                                 const float* __restrict__ a2, const float* __restrict__ b2,
                                                 float* __restrict__ pp) {
    int g = blockIdx.x >> 3, ck = blockIdx.x & 7;
    int t = threadIdx.x;
    int c = t & 63, j = t >> 6;
    int beg = gstart[g], end = gstart[g + 1], n = end - beg;
    int cb = beg + (n * ck) / 8, ce = beg + (n * (ck + 1)) / 8;
    float ac = a2[c], bc = b2[c];
    float s = 0.f;
    for (int i = cb + j; i < ce; i += 4) {
        float y = ac * x[(size_t)i * 64 + c] + bc;
        s += (y > 0.f ? y : expm1f(y));
    }
    __shared__ float sh[4][64];
    sh[j][c] = s;
    __syncthreads();
    if (j == 0)
        pp[blockIdx.x * 64 + c] = sh[0][c] + sh[1][c] + sh[2][c] + sh[3][c];
}

// ---- pool stage 2: reduce 8 chunks (fixed order) + MLP ----
__global__ __launch_bounds__(64) void pool_mlp_fin(const float* __restrict__ pp, const int* __restrict__ gstart,
                                                   const float* __restrict__ smalls, const int* __restrict__ flag,
                                                   void* __restrict__ outp) {
    int g = blockIdx.x, t = threadIdx.x;
    __shared__ float pooled[64];
    __shared__ float hsh[32];
    float s = 0.f;
    for (int k = 0; k < 8; ++k) s += pp[(g * 8 + k) * 64 + t];
    int n = gstart[g + 1] - gstart[g];
    pooled[t] = s / fmaxf((float)n, 1.0f);
    __syncthreads();
    if (t < 32) {
        float acc = smalls[S_FB1 + t];
        for (int cc = 0; cc < 64; ++cc)
            acc += pooled[cc] * smalls[S_FW1 + cc * 32 + t];
        hsh[t] = acc > 0.f ? acc : expm1f(acc);
    }
    __syncthreads();
    if (t == 0) {
        float o = smalls[S_FB2];
        for (int k = 0; k < 32; ++k) o += hsh[k] * smalls[S_FW2 + k];
        if (flag[0]) ((float*)outp)[g] = o;
        else ((__hip_bfloat16*)outp)[g] = __float2bfloat16(o);
    }
}

extern "C" void kernel_launch(void* const* d_in, const int* in_sizes, int n_in,
                              void* d_out, int out_size, void* d_ws, size_t ws_size,
                              hipStream_t stream) {
    const void* x    = d_in[0];
    const int* ei    = (const int*)d_in[1];
    const int* batch = (const int*)d_in[2];
    const void* ea   = d_in[3];
    const void* W1   = d_in[4];
    const void* as1  = d_in[5];
    const void* ad1  = d_in[6];
    const void* We1  = d_in[7];
    const void* ae1  = d_in[8];
    const void* g1   = d_in[10];
    const void* be1  = d_in[11];
    const void* W2   = d_in[12];
    const void* as2  = d_in[13];
    const void* ad2  = d_in[14];
    const void* We2  = d_in[15];
    const void* ae2  = d_in[16];
    const void* g2   = d_in[18];
    const void* be2  = d_in[19];
    const void* fw1  = d_in[20];
    const void* fb1  = d_in[21];
    const void* fw2  = d_in[22];
    const void* fb2  = d_in[23];

    char* ws = (char*)d_ws;
    __hip_bfloat16* xb   = (__hip_bfloat16*)(ws + XB_OFF);
    __hip_bfloat16* hb1  = (__hip_bfloat16*)(ws + HB1_OFF);
    __hip_bfloat16* agg1 = (__hip_bfloat16*)(ws + AGG1_OFF);
    __hip_bfloat16* hb2  = (__hip_bfloat16*)(ws + HB2_OFF);
    float* out2   = (float*)(ws + OUT2_OFF);
    float* eaf    = (float*)(ws + EAF_OFF);
    __hip_bfloat16* W1bt = (__hip_bfloat16*)(ws + W1BT_OFF);
    __hip_bfloat16* W2bt = (__hip_bfloat16*)(ws + W2BT_OFF);
    int2*  csr_se = (int2*)(ws + CSR_OFF);
    int*   rowptr = (int*)(ws + ROWPTR_OFF);
    int*   gstart = (int*)(ws + GSTART_OFF);
    float* smalls = (float*)(ws + SMALL_OFF);
    float* sbuf   = (float*)(ws + SBUF_OFF);
    float* eap    = (float*)(ws + EAP_OFF);
    float* alsp   = (float*)(ws + ALSP_OFF);
    float* aldp   = (float*)(ws + ALDP_OFF);
    float* pmu1   = (float*)(ws + PMU1_OFF);
    float* pm21   = (float*)(ws + PM21_OFF);
    float* pmu2   = (float*)(ws + PMU2_OFF);
    float* pm22   = (float*)(ws + PM22_OFF);
    float* a1     = (float*)(ws + A1_OFF);
    float* b1     = (float*)(ws + B1_OFF);
    float* a2     = (float*)(ws + A2_OFF);
    float* b2     = (float*)(ws + B2_OFF);
    float* ea_acc = (float*)(ws + EAACC_OFF);
    float* als    = (float*)(ws + ALS_OFF);
    float* ald    = (float*)(ws + ALD_OFF);
    float* pp     = (float*)(ws + PP_OFF);
    int*   deg    = (int*)(ws + DEG_OFF);
    int*   cursor = (int*)(ws + CURS_OFF);
    int*   flag   = (int*)(ws + FLAGZ_OFF);

    hipMemsetAsync(ws + ZERO0_START, 0, ZERO0_SIZE, stream);
    hipMemsetAsync(ws + AGG1_OFF + (size_t)N_NODES * 512 * 2, 0, (MPAD - N_NODES) * 512 * 2, stream);

    detect_dtype<<<256, 256, 0, stream>>>((const unsigned short*)x, flag);
    prep<<<PREP_BLOCKS, 256, 0, stream>>>(flag, x, ea, W1, W2,
                                          as1, ad1, We1, ae1, g1, be1, as2, ad2,
                                          We2, ae2, g2, be2, fw1, fb1, fw2, fb2,
                                          xb, eaf, eap, W1bt, W2bt, smalls, sbuf);

    hist_bounds<<<HIST_BLOCKS + 79, 256, 0, stream>>>(ei, deg, batch, gstart);
    deg_scan<<<1, 1024, 0, stream>>>(deg, rowptr, eap, ea_acc);
    edge_scatter<<<HIST_BLOCKS, 256, 0, stream>>>(ei, rowptr, cursor, csr_se);
    csr_sort<<<N_NODES, 64, 0, stream>>>(rowptr, csr_se);
    csr_fill<<<HIST_BLOCKS, 256, 0, stream>>>(csr_se, eaf, ea_acc);

    // ---------- layer 1 ----------
    gemm_mfma_al<false><<<dim3(512 / 64, MPAD / 128), 256, 0, stream>>>(
        (const short*)xb, (const short*)W1bt, hb1, 512, 256,
        alsp, aldp, smalls + S_AS1, smalls + S_AD1, 7, nullptr, nullptr);
    al_combine<<<(MPAD * 4 + 255) / 256, 256, 0, stream>>>(alsp, aldp, als, ald, 2);
    fused_agg1<<<N_NODES, 128, 0, stream>>>(rowptr, csr_se, als, ald, sbuf, hb1, agg1);
    bn_part_b<<<256, 256, 0, stream>>>(agg1, pmu1, pm21);
    bn_reduce_affine<<<2, 256, 0, stream>>>(pmu1, pm21, smalls, S_G1, S_BE1, a1, b1, 512);

    // ---------- layer 2 (BN1+ELU fused into A-staging) ----------
    gemm_mfma_al<true><<<dim3(256 / 64, MPAD / 128), 256, 0, stream>>>(
        (const short*)agg1, (const short*)W2bt, hb2, 256, 512,
        alsp, aldp, smalls + S_AS2, smalls + S_AD2, 6, a1, b1);
    al_combine<<<(MPAD * 4 + 255) / 256, 256, 0, stream>>>(alsp, aldp, als, ald, 1);
    fused_agg2<<<N_NODES, 64, 0, stream>>>(rowptr, csr_se, als, ald, sbuf, hb2, out2);
    bn2_stats<<<256, 256, 0, stream>>>(out2, pmu2, pm22);
    bn_reduce_affine<<<1, 64, 0, stream>>>(pmu2, pm22, smalls, S_G2, S_BE2, a2, b2, 64);

    // ---------- BN2+ELU+pool (2-stage) + MLP ----------
    pool_part<<<N_GRAPHS * 8, 256, 0, stream>>>(out2, gstart, a2, b2, pp);
    pool_mlp_fin<<<N_GRAPHS, 64, 0, stream>>>(pp, gstart, smalls, flag, d_out);
}

// Round 14
// 449.071 us; speedup vs baseline: 1.0186x; 1.0186x over previous
//
#include <hip/hip_runtime.h>
#include <hip/hip_bf16.h>

#define N_NODES  20000
#define MPAD     20096
#define N_EDGES  320000
#define N_EP     (N_EDGES + N_NODES)
#define D_IN     256
#define N_GRAPHS 32
#define HH1 4
#define CC1 128
#define HH2 4
#define CC2 64
#define MAXDEG   128

// ---- workspace layout (bytes) ----
#define XB_OFF      0ull                    // 10,289,152 : x bf16 [MPAD,256]
#define HB1_OFF     10289152ull             // 20,578,304 : h1 bf16 [MPAD,512]
#define AGG1_OFF    30867456ull             // 20,578,304 : agg1 bf16 [MPAD,512] (in-place BN)
#define HB2_OFF     51445760ull             // 10,289,152 : h2 bf16 [MPAD,256]
#define OUT2_OFF    61734912ull             //  5,120,000 : head-mean fp32 [20000,64] (pre-BN)
#define EAF_OFF     66854912ull             //  1,280,000
#define W1BT_OFF    68134912ull             //    262,144
#define W2BT_OFF    68397056ull             //    262,144
#define CSR_OFF     68659200ull             //  2,720,000 (int2: s, edge-id -> s, eav-bits)
#define ROWPTR_OFF  71379200ull             //     80,064
#define GSTART_OFF  71459264ull             //        256
#define SMALL_OFF   71459520ull             //     25,600
#define SBUF_OFF    71485120ull             //         64
#define EAP_OFF     71485184ull             //      1,280
#define ALSP_OFF    71486464ull             //    643,072 : al partials [MPAD*4][2]
#define ALDP_OFF    72129536ull             //    643,072
#define PMU1_OFF    72772608ull             //    524,288
#define PM21_OFF    73296896ull             //    524,288
#define PMU2_OFF    73821184ull             //     65,536
#define PM22_OFF    73886720ull             //     65,536
#define A1_OFF      73952256ull             //      2,048
#define B1_OFF      73954304ull             //      2,048
#define A2_OFF      73956352ull             //        256
#define B2_OFF      73956608ull             //        256
#define EAACC_OFF   73956864ull             //         64
#define ALS_OFF     73956928ull             //    321,536 : combined als [MPAD*4]
#define ALD_OFF     74278464ull             //    321,536
// ---- zeroed-at-start region ----
#define DEG_OFF     74600000ull             //     80,000
#define CURS_OFF    74680000ull             //     80,000
#define FLAGZ_OFF   74760000ull             //        128
#define ZERO0_START DEG_OFF
#define ZERO0_SIZE  160128ull
#define PP_OFF      74760128ull             //     65,536 : pool partials [256][64]

// small-region float offsets
#define S_AS1 0
#define S_AD1 512
#define S_WE1 1024
#define S_AE1 1536
#define S_G1  2048
#define S_BE1 2560
#define S_AS2 3072
#define S_AD2 3328
#define S_WE2 3584
#define S_AE2 3840
#define S_G2  4096
#define S_BE2 4160
#define S_FW1 4224
#define S_FB1 6272
#define S_FW2 6304
#define S_FB2 6336

typedef __attribute__((ext_vector_type(8))) short bf8_t;
typedef __attribute__((ext_vector_type(4))) float f4_t;

// ---- detect fp32 (1) vs bf16 (0); flag pre-zeroed ----
__global__ void detect_dtype(const unsigned short* __restrict__ xr, int* __restrict__ flag) {
    int i = blockIdx.x * blockDim.x + threadIdx.x;
    unsigned short u = xr[i];
    if ((u & 0x7F80) == 0x7F80) atomicOr(flag, 1);
}

__device__ __forceinline__ float loadF(const void* p, int i, int fp32) {
    return fp32 ? ((const float*)p)[i]
                : __bfloat162float(((const __hip_bfloat16*)p)[i]);
}

// ---- fused prep ----
#define PB_XB  5024
#define PB_EAF 313
#define PB_W   512
#define PB_SM  16
#define PREP_BLOCKS (PB_XB + PB_EAF + 2 * PB_W + PB_SM + 1)
__global__ __launch_bounds__(256) void prep(
        const int* __restrict__ flag,
        const void* x, const void* ea, const void* W1, const void* W2,
        const void* as1, const void* ad1, const void* We1, const void* ae1,
        const void* g1, const void* be1, const void* as2, const void* ad2,
        const void* We2, const void* ae2, const void* g2, const void* be2,
        const void* fw1, const void* fb1, const void* fw2, const void* fb2,
        __hip_bfloat16* __restrict__ xb, float* __restrict__ eaf, float* __restrict__ eap,
        __hip_bfloat16* __restrict__ W1bt, __hip_bfloat16* __restrict__ W2bt,
        float* __restrict__ smalls, float* __restrict__ sbuf) {
    __shared__ float sh[256];
    int b = blockIdx.x, t = threadIdx.x;
    int fp32 = flag[0];
    if (b < PB_XB) {
        int base = (b * 256 + t) * 4;
        __hip_bfloat16 tmp[4];
#pragma unroll
        for (int j = 0; j < 4; ++j) {
            int i = base + j;
            float v = (i < N_NODES * D_IN) ? loadF(x, i, fp32) : 0.f;
            tmp[j] = __float2bfloat16(v);
        }
        *(uint2*)&xb[base] = *(uint2*)tmp;
        return;
    }
    b -= PB_XB;
    if (b < PB_EAF) {
        int base = (b * 256 + t) * 4;
        float s = 0.f;
#pragma unroll
        for (int j = 0; j < 4; ++j) {
            int i = base + j;
            if (i < N_EDGES) { float v = loadF(ea, i, fp32); eaf[i] = v; s += v; }
        }
        sh[t] = s;
        __syncthreads();
        for (int st = 128; st; st >>= 1) {
            if (t < st) sh[t] += sh[t + st];
            __syncthreads();
        }
        if (t == 0) eap[b] = sh[0];
        return;
    }
    b -= PB_EAF;
    if (b < PB_W) {
        int i = b * 256 + t;
        int k = i >> 9, n = i & 511;
        W1bt[(size_t)n * 256 + k] = __float2bfloat16(loadF(W1, i, fp32));
        return;
    }
    b -= PB_W;
    if (b < PB_W) {
        int i = b * 256 + t;
        int k = i >> 8, n = i & 255;
        W2bt[(size_t)n * 512 + k] = __float2bfloat16(loadF(W2, i, fp32));
        return;
    }
    b -= PB_W;
    if (b < PB_SM) {
        const void* srcs[16] = {as1, ad1, We1, ae1, g1, be1, as2, ad2, We2, ae2, g2, be2, fw1, fb1, fw2, fb2};
        const int cnts[16] = {512, 512, 512, 512, 512, 512, 256, 256, 256, 256, 64, 64, 2048, 32, 32, 1};
        const int offs[16] = {S_AS1, S_AD1, S_WE1, S_AE1, S_G1, S_BE1, S_AS2, S_AD2,
                              S_WE2, S_AE2, S_G2, S_BE2, S_FW1, S_FB1, S_FW2, S_FB2};
        for (int i = t; i < cnts[b]; i += 256)
            smalls[offs[b] + i] = loadF(srcs[b], i, fp32);
        return;
    }
    if (t < 4) {
        float s = 0.f;
        for (int c = 0; c < CC1; ++c) s += loadF(We1, t * CC1 + c, fp32) * loadF(ae1, t * CC1 + c, fp32);
        sbuf[t] = s;
    } else if (t < 8) {
        int h = t - 4;
        float s = 0.f;
        for (int c = 0; c < CC2; ++c) s += loadF(We2, h * CC2 + c, fp32) * loadF(ae2, h * CC2 + c, fp32);
        sbuf[4 + h] = s;
    }
}

// ---- fused hist + graph bounds ----
#define HIST_BLOCKS 1329
__global__ void hist_bounds(const int* __restrict__ ei, int* __restrict__ deg,
                            const int* __restrict__ batch, int* __restrict__ gstart) {
    int b = blockIdx.x, t = threadIdx.x;
    if (b < HIST_BLOCKS) {
        int e = b * 256 + t;
        if (e >= N_EP) return;
        int d = (e < N_EDGES) ? ei[N_EDGES + e] : e - N_EDGES;
        atomicAdd(&deg[d], 1);
        return;
    }
    int i = (b - HIST_BLOCKS) * 256 + t;
    if (i >= N_NODES) return;
    int bb = batch[i];
    if (i == 0) {
        for (int g = 0; g <= bb; ++g) gstart[g] = 0;
    } else {
        int pb = batch[i - 1];
        for (int g = pb + 1; g <= bb; ++g) gstart[g] = i;
    }
    if (i == N_NODES - 1) {
        for (int g = bb + 1; g <= N_GRAPHS; ++g) gstart[g] = N_NODES;
    }
}

__global__ __launch_bounds__(1024) void deg_scan(const int* __restrict__ deg, int* __restrict__ rowptr,
                                                 const float* __restrict__ eap, float* __restrict__ ea_acc) {
    __shared__ int part[1024];
    int t = threadIdx.x;
    int lo = t * 20;
    int hi = lo + 20; if (hi > N_NODES) hi = N_NODES; if (lo > N_NODES) lo = N_NODES;
    int s = 0;
    for (int i = lo; i < hi; ++i) s += deg[i];
    part[t] = s;
    __syncthreads();
    for (int off = 1; off < 1024; off <<= 1) {
        int u = (t >= off) ? part[t - off] : 0;
        __syncthreads();
        if (t >= off) part[t] += u;
        __syncthreads();
    }
    int run = part[t] - s;
    for (int i = lo; i < hi; ++i) { rowptr[i] = run; run += deg[i]; }
    if (hi == N_NODES && lo < N_NODES) rowptr[N_NODES] = run;
    if (t == 0) {
        float es = 0.f;
        for (int i = 0; i < PB_EAF; ++i) es += eap[i];
        ea_acc[0] = es;
    }
}

__global__ void edge_scatter(const int* __restrict__ ei, const int* __restrict__ rowptr,
                             int* __restrict__ cursor, int2* __restrict__ csr_se) {
    int e = blockIdx.x * blockDim.x + threadIdx.x;
    if (e >= N_EP) return;
    int s, d;
    if (e < N_EDGES) { s = ei[e]; d = ei[N_EDGES + e]; }
    else { s = d = e - N_EDGES; }
    int pos = rowptr[d] + atomicAdd(&cursor[d], 1);
    csr_se[pos] = make_int2(s, e);
}

// ---- canonical CSR order: sort each segment by edge id ----
__global__ __launch_bounds__(64) void csr_sort(const int* __restrict__ rowptr, int2* __restrict__ cs) {
    __shared__ int2 buf[128];
    int d = blockIdx.x;
    int beg = rowptr[d], end = rowptr[d + 1], n = end - beg;
    int lane = threadIdx.x;
    if (n <= 1) return;
    if (n <= 128) {
        for (int i = lane; i < n; i += 64) buf[i] = cs[beg + i];
        __syncthreads();
        if (lane == 0) {
            for (int i = 1; i < n; ++i) {
                int2 key = buf[i]; int j = i - 1;
                while (j >= 0 && buf[j].y > key.y) { buf[j + 1] = buf[j]; --j; }
                buf[j + 1] = key;
            }
        }
        __syncthreads();
        for (int i = lane; i < n; i += 64) cs[beg + i] = buf[i];
    } else if (lane == 0) {
        for (int i = beg + 1; i < end; ++i) {
            int2 key = cs[i]; int j = i - 1;
            while (j >= beg && cs[j].y > key.y) { cs[j + 1] = cs[j]; --j; }
            cs[j + 1] = key;
        }
    }
}

// ---- replace edge id with eav (float bits) in CSR (deterministic, in-place) ----
__global__ void csr_fill(int2* __restrict__ cs, const float* __restrict__ eaf,
                         const float* __restrict__ ea_acc) {
    int p = blockIdx.x * blockDim.x + threadIdx.x;
    if (p >= N_EP) return;
    int e = cs[p].y;
    float eav = (e < N_EDGES) ? eaf[e] : ea_acc[0] * (1.0f / N_EDGES);
    cs[p].y = __float_as_int(eav);
}

// ---- MFMA bf16 GEMM + al epilogue via deterministic partial slots ----
__global__ __launch_bounds__(256) void gemm_mfma_al(
        const short* __restrict__ A, const short* __restrict__ Bt,
        __hip_bfloat16* __restrict__ Cb, int N, int K,
        float* __restrict__ alsp, float* __restrict__ aldp,
        const float* __restrict__ asv, const float* __restrict__ adv, int cshift) {
    __shared__ short As[128 * 40];
    __shared__ short Bs[64 * 40];
    int t = threadIdx.x;
    int wv = t >> 6, lane = t & 63, quad = lane >> 4, lr = lane & 15;
    int m0 = blockIdx.y * 128, n0 = blockIdx.x * 64;
    f4_t acc[2][4] = {};
    int ra0 = t >> 2, sa0 = t & 3;
    int ra1 = (t + 256) >> 2;
    for (int k0 = 0; k0 < K; k0 += 32) {
        *(uint4*)&As[ra0 * 40 + sa0 * 8] = *(const uint4*)&A[(size_t)(m0 + ra0) * K + k0 + sa0 * 8];
        *(uint4*)&As[ra1 * 40 + sa0 * 8] = *(const uint4*)&A[(size_t)(m0 + ra1) * K + k0 + sa0 * 8];
        *(uint4*)&Bs[ra0 * 40 + sa0 * 8] = *(const uint4*)&Bt[(size_t)(n0 + ra0) * K + k0 + sa0 * 8];
        __syncthreads();
        bf8_t a0 = *(const bf8_t*)&As[(wv * 16 + lr) * 40 + quad * 8];
        bf8_t a1 = *(const bf8_t*)&As[((wv + 4) * 16 + lr) * 40 + quad * 8];
#pragma unroll
        for (int nt = 0; nt < 4; ++nt) {
            bf8_t b = *(const bf8_t*)&Bs[(nt * 16 + lr) * 40 + quad * 8];
            acc[0][nt] = __builtin_amdgcn_mfma_f32_16x16x32_bf16(a0, b, acc[0][nt], 0, 0, 0);
            acc[1][nt] = __builtin_amdgcn_mfma_f32_16x16x32_bf16(a1, b, acc[1][nt], 0, 0, 0);
        }
        __syncthreads();
    }
#pragma unroll
    for (int si = 0; si < 2; ++si) {
        int mrow = m0 + (wv + si * 4) * 16 + quad * 4;
#pragma unroll
        for (int nt = 0; nt < 4; ++nt) {
            int col = n0 + nt * 16 + lr;
#pragma unroll
            for (int r = 0; r < 4; ++r)
                Cb[(size_t)(mrow + r) * N + col] = __float2bfloat16(acc[si][nt][r]);
        }
    }
    float asv4[4], adv4[4];
#pragma unroll
    for (int nt = 0; nt < 4; ++nt) {
        asv4[nt] = asv[n0 + nt * 16 + lr];
        adv4[nt] = adv[n0 + nt * 16 + lr];
    }
    int hsel = n0 >> cshift;
    int parity = (n0 >> 6) & ((1 << (cshift - 6)) - 1);
#pragma unroll
    for (int si = 0; si < 2; ++si) {
#pragma unroll
        for (int r = 0; r < 4; ++r) {
            float ps = 0.f, pd = 0.f;
#pragma unroll
            for (int nt = 0; nt < 4; ++nt) {
                ps += acc[si][nt][r] * asv4[nt];
                pd += acc[si][nt][r] * adv4[nt];
            }
#pragma unroll
            for (int m = 1; m < 16; m <<= 1) {
                ps += __shfl_xor(ps, m);
                pd += __shfl_xor(pd, m);
            }
            if (lr == 0) {
                int row = m0 + (wv + si * 4) * 16 + quad * 4 + r;
                alsp[(row * 4 + hsel) * 2 + parity] = ps;
                aldp[(row * 4 + hsel) * 2 + parity] = pd;
            }
        }
    }
}

// ---- combine al partials in fixed order ----
__global__ void al_combine(const float* __restrict__ alsp, const float* __restrict__ aldp,
                           float* __restrict__ als, float* __restrict__ ald, int nparts) {
    int i = blockIdx.x * blockDim.x + threadIdx.x;
    if (i >= MPAD * 4) return;
    float s = alsp[2 * i], d0 = aldp[2 * i];
    if (nparts == 2) { s += alsp[2 * i + 1]; d0 += aldp[2 * i + 1]; }
    als[i] = s; ald[i] = d0;
}

// ---- FUSED deterministic softmax+agg, layer 1: 128 thr/dst, bf16 out [MPAD,512] ----
__global__ __launch_bounds__(128) void fused_agg1(
        const int* __restrict__ rowptr, const int2* __restrict__ cs,
        const float* __restrict__ als, const float* __restrict__ ald,
        const float* __restrict__ sbuf, const __hip_bfloat16* __restrict__ hb,
        __hip_bfloat16* __restrict__ outb) {
    __shared__ float lg[MAXDEG * 4];
    __shared__ int   ssrc[MAXDEG];
    __shared__ float red[4 * 128];
    __shared__ float mxs[4], dns[4];
    int d = blockIdx.x, t = threadIdx.x;
    int beg = rowptr[d], end = rowptr[d + 1], n = end - beg;
    bool fit = (n <= MAXDEG);
    float4 adv = *(const float4*)&ald[d * 4];
    float adh[4] = {adv.x, adv.y, adv.z, adv.w};
    float sb[4] = {sbuf[0], sbuf[1], sbuf[2], sbuf[3]};
    float mx[4] = {-INFINITY, -INFINITY, -INFINITY, -INFINITY};
    for (int p = t; p < n; p += 128) {
        int2 se = cs[beg + p];
        float eav = __int_as_float(se.y);
        float4 as = *(const float4*)&als[se.x * 4];
        float as4[4] = {as.x, as.y, as.z, as.w};
#pragma unroll
        for (int h = 0; h < 4; ++h) {
            float l = as4[h] + adh[h] + eav * sb[h];
            l = l > 0.f ? l : 0.2f * l;
            if (fit) lg[p * 4 + h] = l;
            mx[h] = fmaxf(mx[h], l);
        }
        if (fit) ssrc[p] = se.x;
    }
#pragma unroll
    for (int i = 0; i < 4; ++i) red[i * 128 + t] = mx[i];
    __syncthreads();
    for (int s = 64; s; s >>= 1) {
        if (t < s) {
#pragma unroll
            for (int i = 0; i < 4; ++i)
                red[i * 128 + t] = fmaxf(red[i * 128 + t], red[i * 128 + t + s]);
        }
        __syncthreads();
    }
    if (t < 4) mxs[t] = red[t * 128];
    __syncthreads();
    float m4[4] = {mxs[0], mxs[1], mxs[2], mxs[3]};
    float sm[4] = {0.f, 0.f, 0.f, 0.f};
    if (fit) {
        for (int p = t; p < n; p += 128) {
            float4 lv = *(float4*)&lg[p * 4];
            lv.x = __expf(lv.x - m4[0]); lv.y = __expf(lv.y - m4[1]);
            lv.z = __expf(lv.z - m4[2]); lv.w = __expf(lv.w - m4[3]);
            *(float4*)&lg[p * 4] = lv;
            sm[0] += lv.x; sm[1] += lv.y; sm[2] += lv.z; sm[3] += lv.w;
        }
    } else {
        for (int p = t; p < n; p += 128) {
            int2 se = cs[beg + p];
            float eav = __int_as_float(se.y);
            float4 as = *(const float4*)&als[se.x * 4];
            float as4[4] = {as.x, as.y, as.z, as.w};
#pragma unroll
            for (int h = 0; h < 4; ++h) {
                float l = as4[h] + adh[h] + eav * sb[h];
                l = l > 0.f ? l : 0.2f * l;
                sm[h] += __expf(l - m4[h]);
            }
        }
    }
    __syncthreads();
#pragma unroll
    for (int i = 0; i < 4; ++i) red[i * 128 + t] = sm[i];
    __syncthreads();
    for (int s = 64; s; s >>= 1) {
        if (t < s) {
#pragma unroll
            for (int i = 0; i < 4; ++i)
                red[i * 128 + t] += red[i * 128 + t + s];
        }
        __syncthreads();
    }
    if (t < 4) dns[t] = red[t * 128];
    __syncthreads();
    int h = t >> 5;
    float rdn = 1.0f / (dns[h] + 1e-16f);
    float a0 = 0.f, a1 = 0.f, a2 = 0.f, a3 = 0.f;
    if (fit) {
        for (int p = 0; p < n; ++p) {
            float w = lg[p * 4 + h];
            uint2 raw = *(const uint2*)&hb[(size_t)ssrc[p] * 512 + 4 * t];
            a0 += w * __uint_as_float(raw.x << 16);
            a1 += w * __uint_as_float(raw.x & 0xFFFF0000u);
            a2 += w * __uint_as_float(raw.y << 16);
            a3 += w * __uint_as_float(raw.y & 0xFFFF0000u);
        }
    } else {
        for (int p = 0; p < n; ++p) {
            int2 se = cs[beg + p];
            float eav = __int_as_float(se.y);
            float l = als[se.x * 4 + h] + adh[h] + eav * sb[h];
            l = l > 0.f ? l : 0.2f * l;
            float w = __expf(l - m4[h]);
            uint2 raw = *(const uint2*)&hb[(size_t)se.x * 512 + 4 * t];
            a0 += w * __uint_as_float(raw.x << 16);
            a1 += w * __uint_as_float(raw.x & 0xFFFF0000u);
            a2 += w * __uint_as_float(raw.y << 16);
            a3 += w * __uint_as_float(raw.y & 0xFFFF0000u);
        }
    }
    __hip_bfloat16 tmp[4] = {__float2bfloat16(a0 * rdn), __float2bfloat16(a1 * rdn),
                             __float2bfloat16(a2 * rdn), __float2bfloat16(a3 * rdn)};
    *(uint2*)&outb[(size_t)d * 512 + 4 * t] = *(uint2*)tmp;
}

// ---- FUSED softmax+agg+head-mean, layer 2: 64 thr/dst, fp32 out [20000,64] ----
__global__ __launch_bounds__(64) void fused_agg2(
        const int* __restrict__ rowptr, const int2* __restrict__ cs,
        const float* __restrict__ als, const float* __restrict__ ald,
        const float* __restrict__ sbuf, const __hip_bfloat16* __restrict__ hb,
        float* __restrict__ out2) {
    __shared__ float lg[MAXDEG * 4];
    __shared__ int   ssrc[MAXDEG];
    __shared__ float red[4 * 64];
    __shared__ float mxs[4], dns[4];
    __shared__ float shm[256];
    int d = blockIdx.x, t = threadIdx.x;
    int beg = rowptr[d], end = rowptr[d + 1], n = end - beg;
    bool fit = (n <= MAXDEG);
    float4 adv = *(const float4*)&ald[d * 4];
    float adh[4] = {adv.x, adv.y, adv.z, adv.w};
    float sb[4] = {sbuf[4], sbuf[5], sbuf[6], sbuf[7]};
    float mx[4] = {-INFINITY, -INFINITY, -INFINITY, -INFINITY};
    for (int p = t; p < n; p += 64) {
        int2 se = cs[beg + p];
        float eav = __int_as_float(se.y);
        float4 as = *(const float4*)&als[se.x * 4];
        float as4[4] = {as.x, as.y, as.z, as.w};
#pragma unroll
        for (int h = 0; h < 4; ++h) {
            float l = as4[h] + adh[h] + eav * sb[h];
            l = l > 0.f ? l : 0.2f * l;
            if (fit) lg[p * 4 + h] = l;
            mx[h] = fmaxf(mx[h], l);
        }
        if (fit) ssrc[p] = se.x;
    }
#pragma unroll
    for (int i = 0; i < 4; ++i) red[i * 64 + t] = mx[i];
    __syncthreads();
    for (int s = 32; s; s >>= 1) {
        if (t < s) {
#pragma unroll
            for (int i = 0; i < 4; ++i)
                red[i * 64 + t] = fmaxf(red[i * 64 + t], red[i * 64 + t + s]);
        }
        __syncthreads();
    }
    if (t < 4) mxs[t] = red[t * 64];
    __syncthreads();
    float m4[4] = {mxs[0], mxs[1], mxs[2], mxs[3]};
    float sm[4] = {0.f, 0.f, 0.f, 0.f};
    if (fit) {
        for (int p = t; p < n; p += 64) {
            float4 lv = *(float4*)&lg[p * 4];
            lv.x = __expf(lv.x - m4[0]); lv.y = __expf(lv.y - m4[1]);
            lv.z = __expf(lv.z - m4[2]); lv.w = __expf(lv.w - m4[3]);
            *(float4*)&lg[p * 4] = lv;
            sm[0] += lv.x; sm[1] += lv.y; sm[2] += lv.z; sm[3] += lv.w;
        }
    } else {
        for (int p = t; p < n; p += 64) {
            int2 se = cs[beg + p];
            float eav = __int_as_float(se.y);
            float4 as = *(const float4*)&als[se.x * 4];
            float as4[4] = {as.x, as.y, as.z, as.w};
#pragma unroll
            for (int h = 0; h < 4; ++h) {
                float l = as4[h] + adh[h] + eav * sb[h];
                l = l > 0.f ? l : 0.2f * l;
                sm[h] += __expf(l - m4[h]);
            }
        }
    }
    __syncthreads();
#pragma unroll
    for (int i = 0; i < 4; ++i) red[i * 64 + t] = sm[i];
    __syncthreads();
    for (int s = 32; s; s >>= 1) {
        if (t < s) {
#pragma unroll
            for (int i = 0; i < 4; ++i)
                red[i * 64 + t] += red[i * 64 + t + s];
        }
        __syncthreads();
    }
    if (t < 4) dns[t] = red[t * 64];
    __syncthreads();
    int h = t >> 4;
    float rdn = 1.0f / (dns[h] + 1e-16f);
    float a0 = 0.f, a1 = 0.f, a2 = 0.f, a3 = 0.f;
    if (fit) {
        for (int p = 0; p < n; ++p) {
            float w = lg[p * 4 + h];
            uint2 raw = *(const uint2*)&hb[(size_t)ssrc[p] * 256 + 4 * t];
            a0 += w * __uint_as_float(raw.x << 16);
            a1 += w * __uint_as_float(raw.x & 0xFFFF0000u);
            a2 += w * __uint_as_float(raw.y << 16);
            a3 += w * __uint_as_float(raw.y & 0xFFFF0000u);
        }
    } else {
        for (int p = 0; p < n; ++p) {
            int2 se = cs[beg + p];
            float eav = __int_as_float(se.y);
            float l = als[se.x * 4 + h] + adh[h] + eav * sb[h];
            l = l > 0.f ? l : 0.2f * l;
            float w = __expf(l - m4[h]);
            uint2 raw = *(const uint2*)&hb[(size_t)se.x * 256 + 4 * t];
            a0 += w * __uint_as_float(raw.x << 16);
            a1 += w * __uint_as_float(raw.x & 0xFFFF0000u);
            a2 += w * __uint_as_float(raw.y << 16);
            a3 += w * __uint_as_float(raw.y & 0xFFFF0000u);
        }
    }
    shm[4 * t] = a0 * rdn; shm[4 * t + 1] = a1 * rdn;
    shm[4 * t + 2] = a2 * rdn; shm[4 * t + 3] = a3 * rdn;
    __syncthreads();
    if (t < 16) {
        float4 v;
        v.x = 0.25f * (shm[4 * t] + shm[64 + 4 * t] + shm[128 + 4 * t] + shm[192 + 4 * t]);
        v.y = 0.25f * (shm[4 * t + 1] + shm[64 + 4 * t + 1] + shm[128 + 4 * t + 1] + shm[192 + 4 * t + 1]);
        v.z = 0.25f * (shm[4 * t + 2] + shm[64 + 4 * t + 2] + shm[128 + 4 * t + 2] + shm[192 + 4 * t + 2]);
        v.w = 0.25f * (shm[4 * t + 3] + shm[64 + 4 * t + 3] + shm[128 + 4 * t + 3] + shm[192 + 4 * t + 3]);
        *(float4*)&out2[(size_t)d * 64 + 4 * t] = v;
    }
}

// ---- BN1 stats: per-block partials ----
__global__ __launch_bounds__(256) void bn_part_b(const __hip_bfloat16* __restrict__ x,
                                                 float* __restrict__ pmu, float* __restrict__ pm2) {
    int t = threadIdx.x, b = blockIdx.x;
    float s0 = 0.f, s20 = 0.f, s1 = 0.f, s21 = 0.f;
    for (int i = b; i < N_NODES; i += gridDim.x) {
        unsigned u = *(const unsigned*)&x[(size_t)i * 512 + 2 * t];
        float v0 = __uint_as_float(u << 16);
        float v1 = __uint_as_float(u & 0xFFFF0000u);
        s0 += v0; s20 += v0 * v0; s1 += v1; s21 += v1 * v1;
    }
    pmu[b * 512 + 2 * t] = s0;     pm2[b * 512 + 2 * t] = s20;
    pmu[b * 512 + 2 * t + 1] = s1; pm2[b * 512 + 2 * t + 1] = s21;
}

// ---- reduce partials -> affine a,b (fixed order) ----
__global__ void bn_reduce_affine(const float* __restrict__ pmu, const float* __restrict__ pm2,
                                 const float* __restrict__ smalls, int s_g, int s_be,
                                 float* __restrict__ a, float* __restrict__ b, int nch) {
    int c = blockIdx.x * blockDim.x + threadIdx.x;
    if (c >= nch) return;
    float s = 0.f, s2 = 0.f;
    for (int bk = 0; bk < 256; ++bk) { s += pmu[bk * nch + c]; s2 += pm2[bk * nch + c]; }
    float m = s * (1.0f / N_NODES);
    float var = s2 * (1.0f / N_NODES) - m * m;
    float aa = smalls[s_g + c] * rsqrtf(var + 1e-5f);
    a[c] = aa;
    b[c] = smalls[s_be + c] - m * aa;
}

// ---- BN1 apply + ELU in place on bf16 [N_NODES,512] ----
__global__ __launch_bounds__(256) void bn_apply_elu_b16(__hip_bfloat16* __restrict__ x,
                                                        const float* __restrict__ a,
                                                        const float* __restrict__ b) {
    int q = blockIdx.x * blockDim.x + threadIdx.x;
    if (q >= N_NODES * 512 / 4) return;
    int base = q * 4;
    int j = base & 511;
    uint2 raw = *(uint2*)&x[base];
    float v[4] = {__uint_as_float(raw.x << 16), __uint_as_float(raw.x & 0xFFFF0000u),
                  __uint_as_float(raw.y << 16), __uint_as_float(raw.y & 0xFFFF0000u)};
    __hip_bfloat16 tmp[4];
#pragma unroll
    for (int k = 0; k < 4; ++k) {
        float y = a[j + k] * v[k] + b[j + k];
        y = y > 0.f ? y : expm1f(y);
        tmp[k] = __float2bfloat16(y);
    }
    *(uint2*)&x[base] = *(uint2*)tmp;
}

// ---- BN2 stats: per-block partials ----
__global__ __launch_bounds__(256) void bn2_stats(const float* __restrict__ x,
                                                 float* __restrict__ pmu, float* __restrict__ pm2) {
    int t = threadIdx.x;
    int c = t & 63, j = t >> 6;
    float ls = 0.f, ls2 = 0.f;
    for (int nd = blockIdx.x * 4 + j; nd < N_NODES; nd += gridDim.x * 4) {
        float v = x[(size_t)nd * 64 + c];
        ls += v; ls2 += v * v;
    }
    __shared__ float shs[4][64], sh2[4][64];
    shs[j][c] = ls; sh2[j][c] = ls2;
    __syncthreads();
    if (j == 0) {
        pmu[blockIdx.x * 64 + c] = shs[0][c] + shs[1][c] + shs[2][c] + shs[3][c];
        pm2[blockIdx.x * 64 + c] = sh2[0][c] + sh2[1][c] + sh2[2][c] + sh2[3][c];
    }
}

// ---- pool stage 1: 8 chunks per graph, BN2 affine+ELU fused, partial sums ----
__global__ __launch_bounds__(256) void pool_part(const float* __restrict__ x, const int* __restrict__ gstart,
                                                 const float* __restrict__ a2, const float* __restrict__ b2,
                                                 float* __restrict__ pp) {
    int g = blockIdx.x >> 3, ck = blockIdx.x & 7;
    int t = threadIdx.x;
    int c = t & 63, j = t >> 6;
    int beg = gstart[g], end = gstart[g + 1], n = end - beg;
    int cb = beg + (n * ck) / 8, ce = beg + (n * (ck + 1)) / 8;
    float ac = a2[c], bc = b2[c];
    float s = 0.f;
    for (int i = cb + j; i < ce; i += 4) {
        float y = ac * x[(size_t)i * 64 + c] + bc;
        s += (y > 0.f ? y : expm1f(y));
    }
    __shared__ float sh[4][64];
    sh[j][c] = s;
    __syncthreads();
    if (j == 0)
        pp[blockIdx.x * 64 + c] = sh[0][c] + sh[1][c] + sh[2][c] + sh[3][c];
}

// ---- pool stage 2: reduce 8 chunks (fixed order) + MLP ----
__global__ __launch_bounds__(64) void pool_mlp_fin(const float* __restrict__ pp, const int* __restrict__ gstart,
                                                   const float* __restrict__ smalls, const int* __restrict__ flag,
                                                   void* __restrict__ outp) {
    int g = blockIdx.x, t = threadIdx.x;
    __shared__ float pooled[64];
    __shared__ float hsh[32];
    float s = 0.f;
    for (int k = 0; k < 8; ++k) s += pp[(g * 8 + k) * 64 + t];
    int n = gstart[g + 1] - gstart[g];
    pooled[t] = s / fmaxf((float)n, 1.0f);
    __syncthreads();
    if (t < 32) {
        float acc = smalls[S_FB1 + t];
        for (int cc = 0; cc < 64; ++cc)
            acc += pooled[cc] * smalls[S_FW1 + cc * 32 + t];
        hsh[t] = acc > 0.f ? acc : expm1f(acc);
    }
    __syncthreads();
    if (t == 0) {
        float o = smalls[S_FB2];
        for (int k = 0; k < 32; ++k) o += hsh[k] * smalls[S_FW2 + k];
        if (flag[0]) ((float*)outp)[g] = o;
        else ((__hip_bfloat16*)outp)[g] = __float2bfloat16(o);
    }
}

extern "C" void kernel_launch(void* const* d_in, const int* in_sizes, int n_in,
                              void* d_out, int out_size, void* d_ws, size_t ws_size,
                              hipStream_t stream) {
    const void* x    = d_in[0];
    const int* ei    = (const int*)d_in[1];
    const int* batch = (const int*)d_in[2];
    const void* ea   = d_in[3];
    const void* W1   = d_in[4];
    const void* as1  = d_in[5];
    const void* ad1  = d_in[6];
    const void* We1  = d_in[7];
    const void* ae1  = d_in[8];
    const void* g1   = d_in[10];
    const void* be1  = d_in[11];
    const void* W2   = d_in[12];
    const void* as2  = d_in[13];
    const void* ad2  = d_in[14];
    const void* We2  = d_in[15];
    const void* ae2  = d_in[16];
    const void* g2   = d_in[18];
    const void* be2  = d_in[19];
    const void* fw1  = d_in[20];
    const void* fb1  = d_in[21];
    const void* fw2  = d_in[22];
    const void* fb2  = d_in[23];

    char* ws = (char*)d_ws;
    __hip_bfloat16* xb   = (__hip_bfloat16*)(ws + XB_OFF);
    __hip_bfloat16* hb1  = (__hip_bfloat16*)(ws + HB1_OFF);
    __hip_bfloat16* agg1 = (__hip_bfloat16*)(ws + AGG1_OFF);
    __hip_bfloat16* hb2  = (__hip_bfloat16*)(ws + HB2_OFF);
    float* out2   = (float*)(ws + OUT2_OFF);
    float* eaf    = (float*)(ws + EAF_OFF);
    __hip_bfloat16* W1bt = (__hip_bfloat16*)(ws + W1BT_OFF);
    __hip_bfloat16* W2bt = (__hip_bfloat16*)(ws + W2BT_OFF);
    int2*  csr_se = (int2*)(ws + CSR_OFF);
    int*   rowptr = (int*)(ws + ROWPTR_OFF);
    int*   gstart = (int*)(ws + GSTART_OFF);
    float* smalls = (float*)(ws + SMALL_OFF);
    float* sbuf   = (float*)(ws + SBUF_OFF);
    float* eap    = (float*)(ws + EAP_OFF);
    float* alsp   = (float*)(ws + ALSP_OFF);
    float* aldp   = (float*)(ws + ALDP_OFF);
    float* pmu1   = (float*)(ws + PMU1_OFF);
    float* pm21   = (float*)(ws + PM21_OFF);
    float* pmu2   = (float*)(ws + PMU2_OFF);
    float* pm22   = (float*)(ws + PM22_OFF);
    float* a1     = (float*)(ws + A1_OFF);
    float* b1     = (float*)(ws + B1_OFF);
    float* a2     = (float*)(ws + A2_OFF);
    float* b2     = (float*)(ws + B2_OFF);
    float* ea_acc = (float*)(ws + EAACC_OFF);
    float* als    = (float*)(ws + ALS_OFF);
    float* ald    = (float*)(ws + ALD_OFF);
    float* pp     = (float*)(ws + PP_OFF);
    int*   deg    = (int*)(ws + DEG_OFF);
    int*   cursor = (int*)(ws + CURS_OFF);
    int*   flag   = (int*)(ws + FLAGZ_OFF);

    hipMemsetAsync(ws + ZERO0_START, 0, ZERO0_SIZE, stream);
    hipMemsetAsync(ws + AGG1_OFF + (size_t)N_NODES * 512 * 2, 0, (MPAD - N_NODES) * 512 * 2, stream);

    detect_dtype<<<256, 256, 0, stream>>>((const unsigned short*)x, flag);
    prep<<<PREP_BLOCKS, 256, 0, stream>>>(flag, x, ea, W1, W2,
                                          as1, ad1, We1, ae1, g1, be1, as2, ad2,
                                          We2, ae2, g2, be2, fw1, fb1, fw2, fb2,
                                          xb, eaf, eap, W1bt, W2bt, smalls, sbuf);

    hist_bounds<<<HIST_BLOCKS + 79, 256, 0, stream>>>(ei, deg, batch, gstart);
    deg_scan<<<1, 1024, 0, stream>>>(deg, rowptr, eap, ea_acc);
    edge_scatter<<<HIST_BLOCKS, 256, 0, stream>>>(ei, rowptr, cursor, csr_se);
    csr_sort<<<N_NODES, 64, 0, stream>>>(rowptr, csr_se);
    csr_fill<<<HIST_BLOCKS, 256, 0, stream>>>(csr_se, eaf, ea_acc);

    // ---------- layer 1 ----------
    gemm_mfma_al<<<dim3(512 / 64, MPAD / 128), 256, 0, stream>>>(
        (const short*)xb, (const short*)W1bt, hb1, 512, 256,
        alsp, aldp, smalls + S_AS1, smalls + S_AD1, 7);
    al_combine<<<(MPAD * 4 + 255) / 256, 256, 0, stream>>>(alsp, aldp, als, ald, 2);
    fused_agg1<<<N_NODES, 128, 0, stream>>>(rowptr, csr_se, als, ald, sbuf, hb1, agg1);
    bn_part_b<<<256, 256, 0, stream>>>(agg1, pmu1, pm21);
    bn_reduce_affine<<<2, 256, 0, stream>>>(pmu1, pm21, smalls, S_G1, S_BE1, a1, b1, 512);
    bn_apply_elu_b16<<<10000, 256, 0, stream>>>(agg1, a1, b1);

    // ---------- layer 2 ----------
    gemm_mfma_al<<<dim3(256 / 64, MPAD / 128), 256, 0, stream>>>(
        (const short*)agg1, (const short*)W2bt, hb2, 256, 512,
        alsp, aldp, smalls + S_AS2, smalls + S_AD2, 6);
    al_combine<<<(MPAD * 4 + 255) / 256, 256, 0, stream>>>(alsp, aldp, als, ald, 1);
    fused_agg2<<<N_NODES, 64, 0, stream>>>(rowptr, csr_se, als, ald, sbuf, hb2, out2);
    bn2_stats<<<256, 256, 0, stream>>>(out2, pmu2, pm22);
    bn_reduce_affine<<<1, 64, 0, stream>>>(pmu2, pm22, smalls, S_G2, S_BE2, a2, b2, 64);

    // ---------- BN2+ELU+pool (2-stage) + MLP ----------
    pool_part<<<N_GRAPHS * 8, 256, 0, stream>>>(out2, gstart, a2, b2, pp);
    pool_mlp_fin<<<N_GRAPHS, 64, 0, stream>>>(pp, gstart, smalls, flag, d_out);
}

// Round 15
// 430.591 us; speedup vs baseline: 1.0623x; 1.0429x over previous
//
#include <hip/hip_runtime.h>
#include <hip/hip_bf16.h>

#define N_NODES  20000
#define MPAD     20096
#define N_EDGES  320000
#define N_EP     (N_EDGES + N_NODES)
#define D_IN     256
#define N_GRAPHS 32
#define HH1 4
#define CC1 128
#define HH2 4
#define CC2 64
#define MAXDEG   128

// ---- workspace layout (bytes) ----
#define XB_OFF      0ull                    // 10,289,152 : x bf16 [MPAD,256]
#define HB1_OFF     10289152ull             // 20,578,304 : h1 bf16 [MPAD,512]
#define AGG1_OFF    30867456ull             // 20,578,304 : agg1 bf16 [MPAD,512] (in-place BN)
#define HB2_OFF     51445760ull             // 10,289,152 : h2 bf16 [MPAD,256]
#define OUT2_OFF    61734912ull             //  5,120,000 : head-mean fp32 [20000,64] (pre-BN)
#define EAF_OFF     66854912ull             //  1,280,000
#define W1BT_OFF    68134912ull             //    262,144
#define W2BT_OFF    68397056ull             //    262,144
#define CSR_OFF     68659200ull             //  2,720,000 (int2: s, edge-id -> s, eav-bits)
#define ROWPTR_OFF  71379200ull             //     80,064
#define GSTART_OFF  71459264ull             //        256
#define SMALL_OFF   71459520ull             //     25,600
#define SBUF_OFF    71485120ull             //         64
#define EAP_OFF     71485184ull             //      1,280
#define ALSP_OFF    71486464ull             //    643,072 : al partials [MPAD*4][2]
#define ALDP_OFF    72129536ull             //    643,072
#define PMU1_OFF    72772608ull             //    524,288
#define PM21_OFF    73296896ull             //    524,288
#define PMU2_OFF    73821184ull             //     65,536
#define PM22_OFF    73886720ull             //     65,536
#define A1_OFF      73952256ull             //      2,048
#define B1_OFF      73954304ull             //      2,048
#define A2_OFF      73956352ull             //        256
#define B2_OFF      73956608ull             //        256
#define EAACC_OFF   73956864ull             //         64
#define ALS_OFF     73956928ull             //    321,536 : combined als [MPAD*4]
#define ALD_OFF     74278464ull             //    321,536
// ---- zeroed-at-start region ----
#define DEG_OFF     74600000ull             //     80,000
#define CURS_OFF    74680000ull             //     80,000
#define FLAGZ_OFF   74760000ull             //        128
#define ZERO0_START DEG_OFF
#define ZERO0_SIZE  160128ull
#define PP_OFF      74760128ull             //     65,536 : pool partials [256][64]

// small-region float offsets
#define S_AS1 0
#define S_AD1 512
#define S_WE1 1024
#define S_AE1 1536
#define S_G1  2048
#define S_BE1 2560
#define S_AS2 3072
#define S_AD2 3328
#define S_WE2 3584
#define S_AE2 3840
#define S_G2  4096
#define S_BE2 4160
#define S_FW1 4224
#define S_FB1 6272
#define S_FW2 6304
#define S_FB2 6336

typedef __attribute__((ext_vector_type(8))) short bf8_t;
typedef __attribute__((ext_vector_type(4))) float f4_t;

// ---- detect fp32 (1) vs bf16 (0); flag pre-zeroed ----
__global__ void detect_dtype(const unsigned short* __restrict__ xr, int* __restrict__ flag) {
    int i = blockIdx.x * blockDim.x + threadIdx.x;
    unsigned short u = xr[i];
    if ((u & 0x7F80) == 0x7F80) atomicOr(flag, 1);
}

__device__ __forceinline__ float loadF(const void* p, int i, int fp32) {
    return fp32 ? ((const float*)p)[i]
                : __bfloat162float(((const __hip_bfloat16*)p)[i]);
}

// ---- fused prep ----
#define PB_XB  5024
#define PB_EAF 313
#define PB_W   512
#define PB_SM  16
#define PREP_BLOCKS (PB_XB + PB_EAF + 2 * PB_W + PB_SM + 1)
__global__ __launch_bounds__(256) void prep(
        const int* __restrict__ flag,
        const void* x, const void* ea, const void* W1, const void* W2,
        const void* as1, const void* ad1, const void* We1, const void* ae1,
        const void* g1, const void* be1, const void* as2, const void* ad2,
        const void* We2, const void* ae2, const void* g2, const void* be2,
        const void* fw1, const void* fb1, const void* fw2, const void* fb2,
        __hip_bfloat16* __restrict__ xb, float* __restrict__ eaf, float* __restrict__ eap,
        __hip_bfloat16* __restrict__ W1bt, __hip_bfloat16* __restrict__ W2bt,
        float* __restrict__ smalls, float* __restrict__ sbuf) {
    __shared__ float sh[256];
    int b = blockIdx.x, t = threadIdx.x;
    int fp32 = flag[0];
    if (b < PB_XB) {
        int base = (b * 256 + t) * 4;
        __hip_bfloat16 tmp[4];
#pragma unroll
        for (int j = 0; j < 4; ++j) {
            int i = base + j;
            float v = (i < N_NODES * D_IN) ? loadF(x, i, fp32) : 0.f;
            tmp[j] = __float2bfloat16(v);
        }
        *(uint2*)&xb[base] = *(uint2*)tmp;
        return;
    }
    b -= PB_XB;
    if (b < PB_EAF) {
        int base = (b * 256 + t) * 4;
        float s = 0.f;
#pragma unroll
        for (int j = 0; j < 4; ++j) {
            int i = base + j;
            if (i < N_EDGES) { float v = loadF(ea, i, fp32); eaf[i] = v; s += v; }
        }
        sh[t] = s;
        __syncthreads();
        for (int st = 128; st; st >>= 1) {
            if (t < st) sh[t] += sh[t + st];
            __syncthreads();
        }
        if (t == 0) eap[b] = sh[0];
        return;
    }
    b -= PB_EAF;
    if (b < PB_W) {
        int i = b * 256 + t;
        int k = i >> 9, n = i & 511;
        W1bt[(size_t)n * 256 + k] = __float2bfloat16(loadF(W1, i, fp32));
        return;
    }
    b -= PB_W;
    if (b < PB_W) {
        int i = b * 256 + t;
        int k = i >> 8, n = i & 255;
        W2bt[(size_t)n * 512 + k] = __float2bfloat16(loadF(W2, i, fp32));
        return;
    }
    b -= PB_W;
    if (b < PB_SM) {
        const void* srcs[16] = {as1, ad1, We1, ae1, g1, be1, as2, ad2, We2, ae2, g2, be2, fw1, fb1, fw2, fb2};
        const int cnts[16] = {512, 512, 512, 512, 512, 512, 256, 256, 256, 256, 64, 64, 2048, 32, 32, 1};
        const int offs[16] = {S_AS1, S_AD1, S_WE1, S_AE1, S_G1, S_BE1, S_AS2, S_AD2,
                              S_WE2, S_AE2, S_G2, S_BE2, S_FW1, S_FB1, S_FW2, S_FB2};
        for (int i = t; i < cnts[b]; i += 256)
            smalls[offs[b] + i] = loadF(srcs[b], i, fp32);
        return;
    }
    if (t < 4) {
        float s = 0.f;
        for (int c = 0; c < CC1; ++c) s += loadF(We1, t * CC1 + c, fp32) * loadF(ae1, t * CC1 + c, fp32);
        sbuf[t] = s;
    } else if (t < 8) {
        int h = t - 4;
        float s = 0.f;
        for (int c = 0; c < CC2; ++c) s += loadF(We2, h * CC2 + c, fp32) * loadF(ae2, h * CC2 + c, fp32);
        sbuf[4 + h] = s;
    }
}

// ---- fused hist + graph bounds ----
#define HIST_BLOCKS 1329
__global__ void hist_bounds(const int* __restrict__ ei, int* __restrict__ deg,
                            const int* __restrict__ batch, int* __restrict__ gstart) {
    int b = blockIdx.x, t = threadIdx.x;
    if (b < HIST_BLOCKS) {
        int e = b * 256 + t;
        if (e >= N_EP) return;
        int d = (e < N_EDGES) ? ei[N_EDGES + e] : e - N_EDGES;
        atomicAdd(&deg[d], 1);
        return;
    }
    int i = (b - HIST_BLOCKS) * 256 + t;
    if (i >= N_NODES) return;
    int bb = batch[i];
    if (i == 0) {
        for (int g = 0; g <= bb; ++g) gstart[g] = 0;
    } else {
        int pb = batch[i - 1];
        for (int g = pb + 1; g <= bb; ++g) gstart[g] = i;
    }
    if (i == N_NODES - 1) {
        for (int g = bb + 1; g <= N_GRAPHS; ++g) gstart[g] = N_NODES;
    }
}

__global__ __launch_bounds__(1024) void deg_scan(const int* __restrict__ deg, int* __restrict__ rowptr,
                                                 const float* __restrict__ eap, float* __restrict__ ea_acc) {
    __shared__ int part[1024];
    int t = threadIdx.x;
    int lo = t * 20;
    int hi = lo + 20; if (hi > N_NODES) hi = N_NODES; if (lo > N_NODES) lo = N_NODES;
    int s = 0;
    for (int i = lo; i < hi; ++i) s += deg[i];
    part[t] = s;
    __syncthreads();
    for (int off = 1; off < 1024; off <<= 1) {
        int u = (t >= off) ? part[t - off] : 0;
        __syncthreads();
        if (t >= off) part[t] += u;
        __syncthreads();
    }
    int run = part[t] - s;
    for (int i = lo; i < hi; ++i) { rowptr[i] = run; run += deg[i]; }
    if (hi == N_NODES && lo < N_NODES) rowptr[N_NODES] = run;
    if (t == 0) {
        float es = 0.f;
        for (int i = 0; i < PB_EAF; ++i) es += eap[i];
        ea_acc[0] = es;
    }
}

__global__ void edge_scatter(const int* __restrict__ ei, const int* __restrict__ rowptr,
                             int* __restrict__ cursor, int2* __restrict__ csr_se) {
    int e = blockIdx.x * blockDim.x + threadIdx.x;
    if (e >= N_EP) return;
    int s, d;
    if (e < N_EDGES) { s = ei[e]; d = ei[N_EDGES + e]; }
    else { s = d = e - N_EDGES; }
    int pos = rowptr[d] + atomicAdd(&cursor[d], 1);
    csr_se[pos] = make_int2(s, e);
}

// ---- canonical CSR sort (parallel odd-even, unique keys => deterministic) + eav fill ----
__global__ __launch_bounds__(64) void csr_sort_fill(const int* __restrict__ rowptr, int2* __restrict__ cs,
                                                    const float* __restrict__ eaf,
                                                    const float* __restrict__ ea_acc) {
    __shared__ int2 buf[128];
    int d = blockIdx.x;
    int beg = rowptr[d], end = rowptr[d + 1], n = end - beg;
    int lane = threadIdx.x;
    float ea_mean = ea_acc[0] * (1.0f / N_EDGES);
    if (n <= 0) return;
    if (n <= 128) {
        for (int i = lane; i < n; i += 64) buf[i] = cs[beg + i];
        __syncthreads();
        for (int r = 0; r < n; ++r) {
            int i = 2 * lane + (r & 1);
            if (i + 1 < n) {
                int2 a = buf[i], b = buf[i + 1];
                if (a.y > b.y) { buf[i] = b; buf[i + 1] = a; }
            }
            __syncthreads();
        }
        for (int i = lane; i < n; i += 64) {
            int2 se = buf[i];
            float eav = (se.y < N_EDGES) ? eaf[se.y] : ea_mean;
            se.y = __float_as_int(eav);
            cs[beg + i] = se;
        }
    } else {
        if (lane == 0) {
            for (int i = beg + 1; i < end; ++i) {
                int2 key = cs[i]; int j = i - 1;
                while (j >= beg && cs[j].y > key.y) { cs[j + 1] = cs[j]; --j; }
                cs[j + 1] = key;
            }
        }
        __syncthreads();
        for (int i = lane; i < n; i += 64) {
            int2 se = cs[beg + i];
            float eav = (se.y < N_EDGES) ? eaf[se.y] : ea_mean;
            se.y = __float_as_int(eav);
            cs[beg + i] = se;
        }
    }
}

// ---- MFMA bf16 GEMM + al epilogue via deterministic partial slots ----
__global__ __launch_bounds__(256) void gemm_mfma_al(
        const short* __restrict__ A, const short* __restrict__ Bt,
        __hip_bfloat16* __restrict__ Cb, int N, int K,
        float* __restrict__ alsp, float* __restrict__ aldp,
        const float* __restrict__ asv, const float* __restrict__ adv, int cshift) {
    __shared__ short As[128 * 40];
    __shared__ short Bs[64 * 40];
    int t = threadIdx.x;
    int wv = t >> 6, lane = t & 63, quad = lane >> 4, lr = lane & 15;
    int m0 = blockIdx.y * 128, n0 = blockIdx.x * 64;
    f4_t acc[2][4] = {};
    int ra0 = t >> 2, sa0 = t & 3;
    int ra1 = (t + 256) >> 2;
    for (int k0 = 0; k0 < K; k0 += 32) {
        *(uint4*)&As[ra0 * 40 + sa0 * 8] = *(const uint4*)&A[(size_t)(m0 + ra0) * K + k0 + sa0 * 8];
        *(uint4*)&As[ra1 * 40 + sa0 * 8] = *(const uint4*)&A[(size_t)(m0 + ra1) * K + k0 + sa0 * 8];
        *(uint4*)&Bs[ra0 * 40 + sa0 * 8] = *(const uint4*)&Bt[(size_t)(n0 + ra0) * K + k0 + sa0 * 8];
        __syncthreads();
        bf8_t a0 = *(const bf8_t*)&As[(wv * 16 + lr) * 40 + quad * 8];
        bf8_t a1 = *(const bf8_t*)&As[((wv + 4) * 16 + lr) * 40 + quad * 8];
#pragma unroll
        for (int nt = 0; nt < 4; ++nt) {
            bf8_t b = *(const bf8_t*)&Bs[(nt * 16 + lr) * 40 + quad * 8];
            acc[0][nt] = __builtin_amdgcn_mfma_f32_16x16x32_bf16(a0, b, acc[0][nt], 0, 0, 0);
            acc[1][nt] = __builtin_amdgcn_mfma_f32_16x16x32_bf16(a1, b, acc[1][nt], 0, 0, 0);
        }
        __syncthreads();
    }
#pragma unroll
    for (int si = 0; si < 2; ++si) {
        int mrow = m0 + (wv + si * 4) * 16 + quad * 4;
#pragma unroll
        for (int nt = 0; nt < 4; ++nt) {
            int col = n0 + nt * 16 + lr;
#pragma unroll
            for (int r = 0; r < 4; ++r)
                Cb[(size_t)(mrow + r) * N + col] = __float2bfloat16(acc[si][nt][r]);
        }
    }
    float asv4[4], adv4[4];
#pragma unroll
    for (int nt = 0; nt < 4; ++nt) {
        asv4[nt] = asv[n0 + nt * 16 + lr];
        adv4[nt] = adv[n0 + nt * 16 + lr];
    }
    int hsel = n0 >> cshift;
    int parity = (n0 >> 6) & ((1 << (cshift - 6)) - 1);
#pragma unroll
    for (int si = 0; si < 2; ++si) {
#pragma unroll
        for (int r = 0; r < 4; ++r) {
            float ps = 0.f, pd = 0.f;
#pragma unroll
            for (int nt = 0; nt < 4; ++nt) {
                ps += acc[si][nt][r] * asv4[nt];
                pd += acc[si][nt][r] * adv4[nt];
            }
#pragma unroll
            for (int m = 1; m < 16; m <<= 1) {
                ps += __shfl_xor(ps, m);
                pd += __shfl_xor(pd, m);
            }
            if (lr == 0) {
                int row = m0 + (wv + si * 4) * 16 + quad * 4 + r;
                alsp[(row * 4 + hsel) * 2 + parity] = ps;
                aldp[(row * 4 + hsel) * 2 + parity] = pd;
            }
        }
    }
}

// ---- combine al partials in fixed order ----
__global__ void al_combine(const float* __restrict__ alsp, const float* __restrict__ aldp,
                           float* __restrict__ als, float* __restrict__ ald, int nparts) {
    int i = blockIdx.x * blockDim.x + threadIdx.x;
    if (i >= MPAD * 4) return;
    float s = alsp[2 * i], d0 = aldp[2 * i];
    if (nparts == 2) { s += alsp[2 * i + 1]; d0 += aldp[2 * i + 1]; }
    als[i] = s; ald[i] = d0;
}

// ---- FUSED deterministic softmax+agg, layer 1: 128 thr/dst, bf16 out [MPAD,512] ----
__global__ __launch_bounds__(128) void fused_agg1(
        const int* __restrict__ rowptr, const int2* __restrict__ cs,
        const float* __restrict__ als, const float* __restrict__ ald,
        const float* __restrict__ sbuf, const __hip_bfloat16* __restrict__ hb,
        __hip_bfloat16* __restrict__ outb) {
    __shared__ float lg[MAXDEG * 4];
    __shared__ int   ssrc[MAXDEG];
    __shared__ float red[4 * 128];
    __shared__ float mxs[4], dns[4];
    int d = blockIdx.x, t = threadIdx.x;
    int beg = rowptr[d], end = rowptr[d + 1], n = end - beg;
    bool fit = (n <= MAXDEG);
    float4 adv = *(const float4*)&ald[d * 4];
    float adh[4] = {adv.x, adv.y, adv.z, adv.w};
    float sb[4] = {sbuf[0], sbuf[1], sbuf[2], sbuf[3]};
    float mx[4] = {-INFINITY, -INFINITY, -INFINITY, -INFINITY};
    for (int p = t; p < n; p += 128) {
        int2 se = cs[beg + p];
        float eav = __int_as_float(se.y);
        float4 as = *(const float4*)&als[se.x * 4];
        float as4[4] = {as.x, as.y, as.z, as.w};
#pragma unroll
        for (int h = 0; h < 4; ++h) {
            float l = as4[h] + adh[h] + eav * sb[h];
            l = l > 0.f ? l : 0.2f * l;
            if (fit) lg[p * 4 + h] = l;
            mx[h] = fmaxf(mx[h], l);
        }
        if (fit) ssrc[p] = se.x;
    }
#pragma unroll
    for (int i = 0; i < 4; ++i) red[i * 128 + t] = mx[i];
    __syncthreads();
    for (int s = 64; s; s >>= 1) {
        if (t < s) {
#pragma unroll
            for (int i = 0; i < 4; ++i)
                red[i * 128 + t] = fmaxf(red[i * 128 + t], red[i * 128 + t + s]);
        }
        __syncthreads();
    }
    if (t < 4) mxs[t] = red[t * 128];
    __syncthreads();
    float m4[4] = {mxs[0], mxs[1], mxs[2], mxs[3]};
    float sm[4] = {0.f, 0.f, 0.f, 0.f};
    if (fit) {
        for (int p = t; p < n; p += 128) {
            float4 lv = *(float4*)&lg[p * 4];
            lv.x = __expf(lv.x - m4[0]); lv.y = __expf(lv.y - m4[1]);
            lv.z = __expf(lv.z - m4[2]); lv.w = __expf(lv.w - m4[3]);
            *(float4*)&lg[p * 4] = lv;
            sm[0] += lv.x; sm[1] += lv.y; sm[2] += lv.z; sm[3] += lv.w;
        }
    } else {
        for (int p = t; p < n; p += 128) {
            int2 se = cs[beg + p];
            float eav = __int_as_float(se.y);
            float4 as = *(const float4*)&als[se.x * 4];
            float as4[4] = {as.x, as.y, as.z, as.w};
#pragma unroll
            for (int h = 0; h < 4; ++h) {
                float l = as4[h] + adh[h] + eav * sb[h];
                l = l > 0.f ? l : 0.2f * l;
                sm[h] += __expf(l - m4[h]);
            }
        }
    }
    __syncthreads();
#pragma unroll
    for (int i = 0; i < 4; ++i) red[i * 128 + t] = sm[i];
    __syncthreads();
    for (int s = 64; s; s >>= 1) {
        if (t < s) {
#pragma unroll
            for (int i = 0; i < 4; ++i)
                red[i * 128 + t] += red[i * 128 + t + s];
        }
        __syncthreads();
    }
    if (t < 4) dns[t] = red[t * 128];
    __syncthreads();
    int h = t >> 5;
    float rdn = 1.0f / (dns[h] + 1e-16f);
    float a0 = 0.f, a1 = 0.f, a2 = 0.f, a3 = 0.f;
    if (fit) {
        for (int p = 0; p < n; ++p) {
            float w = lg[p * 4 + h];
            uint2 raw = *(const uint2*)&hb[(size_t)ssrc[p] * 512 + 4 * t];
            a0 += w * __uint_as_float(raw.x << 16);
            a1 += w * __uint_as_float(raw.x & 0xFFFF0000u);
            a2 += w * __uint_as_float(raw.y << 16);
            a3 += w * __uint_as_float(raw.y & 0xFFFF0000u);
        }
    } else {
        for (int p = 0; p < n; ++p) {
            int2 se = cs[beg + p];
            float eav = __int_as_float(se.y);
            float l = als[se.x * 4 + h] + adh[h] + eav * sb[h];
            l = l > 0.f ? l : 0.2f * l;
            float w = __expf(l - m4[h]);
            uint2 raw = *(const uint2*)&hb[(size_t)se.x * 512 + 4 * t];
            a0 += w * __uint_as_float(raw.x << 16);
            a1 += w * __uint_as_float(raw.x & 0xFFFF0000u);
            a2 += w * __uint_as_float(raw.y << 16);
            a3 += w * __uint_as_float(raw.y & 0xFFFF0000u);
        }
    }
    __hip_bfloat16 tmp[4] = {__float2bfloat16(a0 * rdn), __float2bfloat16(a1 * rdn),
                             __float2bfloat16(a2 * rdn), __float2bfloat16(a3 * rdn)};
    *(uint2*)&outb[(size_t)d * 512 + 4 * t] = *(uint2*)tmp;
}

// ---- FUSED softmax+agg+head-mean, layer 2: 64 thr/dst, fp32 out [20000,64] ----
__global__ __launch_bounds__(64) void fused_agg2(
        const int* __restrict__ rowptr, const int2* __restrict__ cs,
        const float* __restrict__ als, const float* __restrict__ ald,
        const float* __restrict__ sbuf, const __hip_bfloat16* __restrict__ hb,
        float* __restrict__ out2) {
    __shared__ float lg[MAXDEG * 4];
    __shared__ int   ssrc[MAXDEG];
    __shared__ float red[4 * 64];
    __shared__ float mxs[4], dns[4];
    __shared__ float shm[256];
    int d = blockIdx.x, t = threadIdx.x;
    int beg = rowptr[d], end = rowptr[d + 1], n = end - beg;
    bool fit = (n <= MAXDEG);
    float4 adv = *(const float4*)&ald[d * 4];
    float adh[4] = {adv.x, adv.y, adv.z, adv.w};
    float sb[4] = {sbuf[4], sbuf[5], sbuf[6], sbuf[7]};
    float mx[4] = {-INFINITY, -INFINITY, -INFINITY, -INFINITY};
    for (int p = t; p < n; p += 64) {
        int2 se = cs[beg + p];
        float eav = __int_as_float(se.y);
        float4 as = *(const float4*)&als[se.x * 4];
        float as4[4] = {as.x, as.y, as.z, as.w};
#pragma unroll
        for (int h = 0; h < 4; ++h) {
            float l = as4[h] + adh[h] + eav * sb[h];
            l = l > 0.f ? l : 0.2f * l;
            if (fit) lg[p * 4 + h] = l;
            mx[h] = fmaxf(mx[h], l);
        }
        if (fit) ssrc[p] = se.x;
    }
#pragma unroll
    for (int i = 0; i < 4; ++i) red[i * 64 + t] = mx[i];
    __syncthreads();
    for (int s = 32; s; s >>= 1) {
        if (t < s) {
#pragma unroll
            for (int i = 0; i < 4; ++i)
                red[i * 64 + t] = fmaxf(red[i * 64 + t], red[i * 64 + t + s]);
        }
        __syncthreads();
    }
    if (t < 4) mxs[t] = red[t * 64];
    __syncthreads();
    float m4[4] = {mxs[0], mxs[1], mxs[2], mxs[3]};
    float sm[4] = {0.f, 0.f, 0.f, 0.f};
    if (fit) {
        for (int p = t; p < n; p += 64) {
            float4 lv = *(float4*)&lg[p * 4];
            lv.x = __expf(lv.x - m4[0]); lv.y = __expf(lv.y - m4[1]);
            lv.z = __expf(lv.z - m4[2]); lv.w = __expf(lv.w - m4[3]);
            *(float4*)&lg[p * 4] = lv;
            sm[0] += lv.x; sm[1] += lv.y; sm[2] += lv.z; sm[3] += lv.w;
        }
    } else {
        for (int p = t; p < n; p += 64) {
            int2 se = cs[beg + p];
            float eav = __int_as_float(se.y);
            float4 as = *(const float4*)&als[se.x * 4];
            float as4[4] = {as.x, as.y, as.z, as.w};
#pragma unroll
            for (int h = 0; h < 4; ++h) {
                float l = as4[h] + adh[h] + eav * sb[h];
                l = l > 0.f ? l : 0.2f * l;
                sm[h] += __expf(l - m4[h]);
            }
        }
    }
    __syncthreads();
#pragma unroll
    for (int i = 0; i < 4; ++i) red[i * 64 + t] = sm[i];
    __syncthreads();
    for (int s = 32; s; s >>= 1) {
        if (t < s) {
#pragma unroll
            for (int i = 0; i < 4; ++i)
                red[i * 64 + t] += red[i * 64 + t + s];
        }
        __syncthreads();
    }
    if (t < 4) dns[t] = red[t * 64];
    __syncthreads();
    int h = t >> 4;
    float rdn = 1.0f / (dns[h] + 1e-16f);
    float a0 = 0.f, a1 = 0.f, a2 = 0.f, a3 = 0.f;
    if (fit) {
        for (int p = 0; p < n; ++p) {
            float w = lg[p * 4 + h];
            uint2 raw = *(const uint2*)&hb[(size_t)ssrc[p] * 256 + 4 * t];
            a0 += w * __uint_as_float(raw.x << 16);
            a1 += w * __uint_as_float(raw.x & 0xFFFF0000u);
            a2 += w * __uint_as_float(raw.y << 16);
            a3 += w * __uint_as_float(raw.y & 0xFFFF0000u);
        }
    } else {
        for (int p = 0; p < n; ++p) {
            int2 se = cs[beg + p];
            float eav = __int_as_float(se.y);
            float l = als[se.x * 4 + h] + adh[h] + eav * sb[h];
            l = l > 0.f ? l : 0.2f * l;
            float w = __expf(l - m4[h]);
            uint2 raw = *(const uint2*)&hb[(size_t)se.x * 256 + 4 * t];
            a0 += w * __uint_as_float(raw.x << 16);
            a1 += w * __uint_as_float(raw.x & 0xFFFF0000u);
            a2 += w * __uint_as_float(raw.y << 16);
            a3 += w * __uint_as_float(raw.y & 0xFFFF0000u);
        }
    }
    shm[4 * t] = a0 * rdn; shm[4 * t + 1] = a1 * rdn;
    shm[4 * t + 2] = a2 * rdn; shm[4 * t + 3] = a3 * rdn;
    __syncthreads();
    if (t < 16) {
        float4 v;
        v.x = 0.25f * (shm[4 * t] + shm[64 + 4 * t] + shm[128 + 4 * t] + shm[192 + 4 * t]);
        v.y = 0.25f * (shm[4 * t + 1] + shm[64 + 4 * t + 1] + shm[128 + 4 * t + 1] + shm[192 + 4 * t + 1]);
        v.z = 0.25f * (shm[4 * t + 2] + shm[64 + 4 * t + 2] + shm[128 + 4 * t + 2] + shm[192 + 4 * t + 2]);
        v.w = 0.25f * (shm[4 * t + 3] + shm[64 + 4 * t + 3] + shm[128 + 4 * t + 3] + shm[192 + 4 * t + 3]);
        *(float4*)&out2[(size_t)d * 64 + 4 * t] = v;
    }
}

// ---- BN1 stats: per-block partials ----
__global__ __launch_bounds__(256) void bn_part_b(const __hip_bfloat16* __restrict__ x,
                                                 float* __restrict__ pmu, float* __restrict__ pm2) {
    int t = threadIdx.x, b = blockIdx.x;
    float s0 = 0.f, s20 = 0.f, s1 = 0.f, s21 = 0.f;
    for (int i = b; i < N_NODES; i += gridDim.x) {
        unsigned u = *(const unsigned*)&x[(size_t)i * 512 + 2 * t];
        float v0 = __uint_as_float(u << 16);
        float v1 = __uint_as_float(u & 0xFFFF0000u);
        s0 += v0; s20 += v0 * v0; s1 += v1; s21 += v1 * v1;
    }
    pmu[b * 512 + 2 * t] = s0;     pm2[b * 512 + 2 * t] = s20;
    pmu[b * 512 + 2 * t + 1] = s1; pm2[b * 512 + 2 * t + 1] = s21;
}

// ---- reduce partials -> affine a,b (fixed order) ----
__global__ void bn_reduce_affine(const float* __restrict__ pmu, const float* __restrict__ pm2,
                                 const float* __restrict__ smalls, int s_g, int s_be,
                                 float* __restrict__ a, float* __restrict__ b, int nch) {
    int c = blockIdx.x * blockDim.x + threadIdx.x;
    if (c >= nch) return;
    float s = 0.f, s2 = 0.f;
    for (int bk = 0; bk < 256; ++bk) { s += pmu[bk * nch + c]; s2 += pm2[bk * nch + c]; }
    float m = s * (1.0f / N_NODES);
    float var = s2 * (1.0f / N_NODES) - m * m;
    float aa = smalls[s_g + c] * rsqrtf(var + 1e-5f);
    a[c] = aa;
    b[c] = smalls[s_be + c] - m * aa;
}

// ---- BN1 apply + ELU in place on bf16 [N_NODES,512] ----
__global__ __launch_bounds__(256) void bn_apply_elu_b16(__hip_bfloat16* __restrict__ x,
                                                        const float* __restrict__ a,
                                                        const float* __restrict__ b) {
    int q = blockIdx.x * blockDim.x + threadIdx.x;
    if (q >= N_NODES * 512 / 4) return;
    int base = q * 4;
    int j = base & 511;
    uint2 raw = *(uint2*)&x[base];
    float v[4] = {__uint_as_float(raw.x << 16), __uint_as_float(raw.x & 0xFFFF0000u),
                  __uint_as_float(raw.y << 16), __uint_as_float(raw.y & 0xFFFF0000u)};
    __hip_bfloat16 tmp[4];
#pragma unroll
    for (int k = 0; k < 4; ++k) {
        float y = a[j + k] * v[k] + b[j + k];
        y = y > 0.f ? y : expm1f(y);
        tmp[k] = __float2bfloat16(y);
    }
    *(uint2*)&x[base] = *(uint2*)tmp;
}

// ---- BN2 stats: per-block partials ----
__global__ __launch_bounds__(256) void bn2_stats(const float* __restrict__ x,
                                                 float* __restrict__ pmu, float* __restrict__ pm2) {
    int t = threadIdx.x;
    int c = t & 63, j = t >> 6;
    float ls = 0.f, ls2 = 0.f;
    for (int nd = blockIdx.x * 4 + j; nd < N_NODES; nd += gridDim.x * 4) {
        float v = x[(size_t)nd * 64 + c];
        ls += v; ls2 += v * v;
    }
    __shared__ float shs[4][64], sh2[4][64];
    shs[j][c] = ls; sh2[j][c] = ls2;
    __syncthreads();
    if (j == 0) {
        pmu[blockIdx.x * 64 + c] = shs[0][c] + shs[1][c] + shs[2][c] + shs[3][c];
        pm2[blockIdx.x * 64 + c] = sh2[0][c] + sh2[1][c] + sh2[2][c] + sh2[3][c];
    }
}

// ---- pool stage 1: 8 chunks per graph, BN2 affine+ELU fused, partial sums ----
__global__ __launch_bounds__(256) void pool_part(const float* __restrict__ x, const int* __restrict__ gstart,
                                                 const float* __restrict__ a2, const float* __restrict__ b2,
                                                 float* __restrict__ pp) {
    int g = blockIdx.x >> 3, ck = blockIdx.x & 7;
    int t = threadIdx.x;
    int c = t & 63, j = t >> 6;
    int beg = gstart[g], end = gstart[g + 1], n = end - beg;
    int cb = beg + (n * ck) / 8, ce = beg + (n * (ck + 1)) / 8;
    float ac = a2[c], bc = b2[c];
    float s = 0.f;
    for (int i = cb + j; i < ce; i += 4) {
        float y = ac * x[(size_t)i * 64 + c] + bc;
        s += (y > 0.f ? y : expm1f(y));
    }
    __shared__ float sh[4][64];
    sh[j][c] = s;
    __syncthreads();
    if (j == 0)
        pp[blockIdx.x * 64 + c] = sh[0][c] + sh[1][c] + sh[2][c] + sh[3][c];
}

// ---- pool stage 2: reduce 8 chunks (fixed order) + MLP ----
__global__ __launch_bounds__(64) void pool_mlp_fin(const float* __restrict__ pp, const int* __restrict__ gstart,
                                                   const float* __restrict__ smalls, const int* __restrict__ flag,
                                                   void* __restrict__ outp) {
    int g = blockIdx.x, t = threadIdx.x;
    __shared__ float pooled[64];
    __shared__ float hsh[32];
    float s = 0.f;
    for (int k = 0; k < 8; ++k) s += pp[(g * 8 + k) * 64 + t];
    int n = gstart[g + 1] - gstart[g];
    pooled[t] = s / fmaxf((float)n, 1.0f);
    __syncthreads();
    if (t < 32) {
        float acc = smalls[S_FB1 + t];
        for (int cc = 0; cc < 64; ++cc)
            acc += pooled[cc] * smalls[S_FW1 + cc * 32 + t];
        hsh[t] = acc > 0.f ? acc : expm1f(acc);
    }
    __syncthreads();
    if (t == 0) {
        float o = smalls[S_FB2];
        for (int k = 0; k < 32; ++k) o += hsh[k] * smalls[S_FW2 + k];
        if (flag[0]) ((float*)outp)[g] = o;
        else ((__hip_bfloat16*)outp)[g] = __float2bfloat16(o);
    }
}

extern "C" void kernel_launch(void* const* d_in, const int* in_sizes, int n_in,
                              void* d_out, int out_size, void* d_ws, size_t ws_size,
                              hipStream_t stream) {
    const void* x    = d_in[0];
    const int* ei    = (const int*)d_in[1];
    const int* batch = (const int*)d_in[2];
    const void* ea   = d_in[3];
    const void* W1   = d_in[4];
    const void* as1  = d_in[5];
    const void* ad1  = d_in[6];
    const void* We1  = d_in[7];
    const void* ae1  = d_in[8];
    const void* g1   = d_in[10];
    const void* be1  = d_in[11];
    const void* W2   = d_in[12];
    const void* as2  = d_in[13];
    const void* ad2  = d_in[14];
    const void* We2  = d_in[15];
    const void* ae2  = d_in[16];
    const void* g2   = d_in[18];
    const void* be2  = d_in[19];
    const void* fw1  = d_in[20];
    const void* fb1  = d_in[21];
    const void* fw2  = d_in[22];
    const void* fb2  = d_in[23];

    char* ws = (char*)d_ws;
    __hip_bfloat16* xb   = (__hip_bfloat16*)(ws + XB_OFF);
    __hip_bfloat16* hb1  = (__hip_bfloat16*)(ws + HB1_OFF);
    __hip_bfloat16* agg1 = (__hip_bfloat16*)(ws + AGG1_OFF);
    __hip_bfloat16* hb2  = (__hip_bfloat16*)(ws + HB2_OFF);
    float* out2   = (float*)(ws + OUT2_OFF);
    float* eaf    = (float*)(ws + EAF_OFF);
    __hip_bfloat16* W1bt = (__hip_bfloat16*)(ws + W1BT_OFF);
    __hip_bfloat16* W2bt = (__hip_bfloat16*)(ws + W2BT_OFF);
    int2*  csr_se = (int2*)(ws + CSR_OFF);
    int*   rowptr = (int*)(ws + ROWPTR_OFF);
    int*   gstart = (int*)(ws + GSTART_OFF);
    float* smalls = (float*)(ws + SMALL_OFF);
    float* sbuf   = (float*)(ws + SBUF_OFF);
    float* eap    = (float*)(ws + EAP_OFF);
    float* alsp   = (float*)(ws + ALSP_OFF);
    float* aldp   = (float*)(ws + ALDP_OFF);
    float* pmu1   = (float*)(ws + PMU1_OFF);
    float* pm21   = (float*)(ws + PM21_OFF);
    float* pmu2   = (float*)(ws + PMU2_OFF);
    float* pm22   = (float*)(ws + PM22_OFF);
    float* a1     = (float*)(ws + A1_OFF);
    float* b1     = (float*)(ws + B1_OFF);
    float* a2     = (float*)(ws + A2_OFF);
    float* b2     = (float*)(ws + B2_OFF);
    float* ea_acc = (float*)(ws + EAACC_OFF);
    float* als    = (float*)(ws + ALS_OFF);
    float* ald    = (float*)(ws + ALD_OFF);
    float* pp     = (float*)(ws + PP_OFF);
    int*   deg    = (int*)(ws + DEG_OFF);
    int*   cursor = (int*)(ws + CURS_OFF);
    int*   flag   = (int*)(ws + FLAGZ_OFF);

    hipMemsetAsync(ws + ZERO0_START, 0, ZERO0_SIZE, stream);

    detect_dtype<<<256, 256, 0, stream>>>((const unsigned short*)x, flag);
    prep<<<PREP_BLOCKS, 256, 0, stream>>>(flag, x, ea, W1, W2,
                                          as1, ad1, We1, ae1, g1, be1, as2, ad2,
                                          We2, ae2, g2, be2, fw1, fb1, fw2, fb2,
                                          xb, eaf, eap, W1bt, W2bt, smalls, sbuf);

    hist_bounds<<<HIST_BLOCKS + 79, 256, 0, stream>>>(ei, deg, batch, gstart);
    deg_scan<<<1, 1024, 0, stream>>>(deg, rowptr, eap, ea_acc);
    edge_scatter<<<HIST_BLOCKS, 256, 0, stream>>>(ei, rowptr, cursor, csr_se);
    csr_sort_fill<<<N_NODES, 64, 0, stream>>>(rowptr, csr_se, eaf, ea_acc);

    // ---------- layer 1 ----------
    gemm_mfma_al<<<dim3(512 / 64, MPAD / 128), 256, 0, stream>>>(
        (const short*)xb, (const short*)W1bt, hb1, 512, 256,
        alsp, aldp, smalls + S_AS1, smalls + S_AD1, 7);
    al_combine<<<(MPAD * 4 + 255) / 256, 256, 0, stream>>>(alsp, aldp, als, ald, 2);
    fused_agg1<<<N_NODES, 128, 0, stream>>>(rowptr, csr_se, als, ald, sbuf, hb1, agg1);
    bn_part_b<<<256, 256, 0, stream>>>(agg1, pmu1, pm21);
    bn_reduce_affine<<<2, 256, 0, stream>>>(pmu1, pm21, smalls, S_G1, S_BE1, a1, b1, 512);
    bn_apply_elu_b16<<<10000, 256, 0, stream>>>(agg1, a1, b1);

    // ---------- layer 2 ----------
    gemm_mfma_al<<<dim3(256 / 64, MPAD / 128), 256, 0, stream>>>(
        (const short*)agg1, (const short*)W2bt, hb2, 256, 512,
        alsp, aldp, smalls + S_AS2, smalls + S_AD2, 6);
    al_combine<<<(MPAD * 4 + 255) / 256, 256, 0, stream>>>(alsp, aldp, als, ald, 1);
    fused_agg2<<<N_NODES, 64, 0, stream>>>(rowptr, csr_se, als, ald, sbuf, hb2, out2);
    bn2_stats<<<256, 256, 0, stream>>>(out2, pmu2, pm22);
    bn_reduce_affine<<<1, 64, 0, stream>>>(pmu2, pm22, smalls, S_G2, S_BE2, a2, b2, 64);

    // ---------- BN2+ELU+pool (2-stage) + MLP ----------
    pool_part<<<N_GRAPHS * 8, 256, 0, stream>>>(out2, gstart, a2, b2, pp);
    pool_mlp_fin<<<N_GRAPHS, 64, 0, stream>>>(pp, gstart, smalls, flag, d_out);
}